// Round 15
// baseline (86.964 us; speedup 1.0000x reference)
//
#include <hip/hip_runtime.h>
#include <hip/hip_bf16.h>
#include <hip/hip_fp16.h>

#define B_    4096
#define ARITY 6
#define EMB   100
#define NF    200
#define FC    1200
#define NROWS (B_*ARITY)      // 24576
#define MPAD  (B_*8)          // 32768 padded M rows (8 per batch, 2 sentinel)
#define NPAD  2432            // N rows of W_h (A/C pairs interleaved)
#define BN_EPS 1e-5f
#define KP    224
#define SENT  32768.0f
#define NTW   (NPAD/4/16)     // 38 tiles of 16 N-rows per wave (o-quarter)

typedef _Float16 half8 __attribute__((ext_vector_type(8)));
typedef float f32x4 __attribute__((ext_vector_type(4)));

// ws float offsets
#define MRAW_OFF 0              // m_raw f16 [24576][200] -> 2,457,600 f
#define WH_OFF   2457600        // W_h f16, tile-major coalesced -> 272,384 f
#define WT_OFF   2729984        // wT  f16 [ks][hi|lo][14 grp][coalesced] -> 50,176 f
#define STAT_OFF 2780160        // gshad[16][400]

__device__ __forceinline__ float4 ld4(const float* rr, const float* vr, int e) {
    if (e < EMB)        return *(const float4*)&rr[e];
    else if (e < 2*EMB) return *(const float4*)&vr[e - EMB];
    float4 z = {0.f,0.f,0.f,0.f}; return z;
}

// ---------------- k0: weight prep + out init -------------------------------
// COALESCED layouts: a wave-load instruction reads contiguous bytes.
// wT  (k1): half-off = ks*14336 + part*7168 + (f>>4)*512 + (f&15)*32 + q*8
// W_h (k3): half-off = (n>>4)*3584 + ks*512 + (n&15)*32 + q*8
#define K0_W1 (224*28)
#define K0_W2 (K0_W1 + NPAD*28)
#define K0_TOT (K0_W2 + B_)
__launch_bounds__(256)
__global__ void k0_prep(const float* __restrict__ cw, const float* __restrict__ gW,
                        const float* __restrict__ fb,
                        _Float16* __restrict__ wT,
                        _Float16* __restrict__ W_h, float* __restrict__ out)
{
    int id = blockIdx.x * 256 + threadIdx.x;
    if (id < K0_W1) {
        int f = id / 28, s = id - f*28;
        int ks = s >> 2, ls = s & 3;
        int off = ks*14336 + (f >> 4)*512 + (f & 15)*32 + ls*8;
        half8 h, l;
        #pragma unroll
        for (int j = 0; j < 8; ++j) {
            int k = s*8 + j;
            float v = (f < NF && k < NF) ? cw[f*NF + k] : 0.f;
            _Float16 hi = (_Float16)v;
            h[j] = hi; l[j] = (_Float16)(v - (float)hi);
        }
        *(half8*)&wT[off] = h;
        *(half8*)&wT[off + 7168] = l;
    } else if (id < K0_W2) {
        int id2 = id - K0_W1;
        int n = id2 / 28, s = id2 - n*28;
        int o = n >> 1, hf = n & 1;
        int off = (n >> 4)*3584 + (s >> 2)*512 + (n & 15)*32 + (s & 3)*8;
        half8 h;
        #pragma unroll
        for (int j = 0; j < 8; ++j) {
            int k = s*8 + j;
            float v = 0.f;
            if (k < NF && n < 2*FC) v = gW[(size_t)o*400 + hf*200 + k];
            if (k == NF) v = SENT;           // sentinel column
            h[j] = (_Float16)v;
        }
        *(half8*)&W_h[off] = h;
    } else if (id < K0_TOT) {
        out[id - K0_W2] = fb[0];
    }
}

// ---------------- k1: gather + split-f16 MFMA conv + stats -----------------
// Grid 768 (M-tile 32), 4 waves (wm = M-half 16 rows, wn = N-half 112 feat).
// k3-style STREAM over nf (7 steps of 16 features): per step
// { LOADW(nf+1) -> 21-chained MFMAs(nf) -> EPI(nf-1) }, register dbuf
// (bh0/bl0, bh1/bl1 static banks) + 2 acc banks. ~196 live VGPR ->
// (256,2); never cap below the live set (round-11 spill lesson).
// Arithmetic per nf identical to round 13/14 -> m_raw bit-identical.
__launch_bounds__(256, 2)
__global__ void k1_mfma(const int* __restrict__ x,
                        const float* __restrict__ er,
                        const float* __restrict__ ev,
                        const _Float16* __restrict__ wT,
                        const float* __restrict__ cb,
                        _Float16* __restrict__ m_raw,
                        float* __restrict__ gshad)
{
    __shared__ __align__(16) char smem[30528];
    _Float16* s_ahi = (_Float16*)smem;          // 32x224
    _Float16* s_alo = s_ahi + 7168;
    float* s_sum = (float*)(smem + 28672);
    float* s_sq  = (float*)(smem + 29472);
    int*   s_ri  = (int*)(smem + 30272);
    int*   s_vi  = (int*)(smem + 30400);

    const int t = threadIdx.x, lane = t & 63, wave = t >> 6;
    const int wm = wave >> 1, wn = wave & 1;
    const int R0 = blockIdx.x * 32;
    const int q = lane >> 4, cx = lane & 15;
    const int rdsw = (q ^ ((cx >> 1) & 3)) * 8;

    if (t < 32) {
        int R = R0 + t, b = R / ARITY, a = R - b * ARITY;
        bool is64 = ((x[1] | x[3] | x[5] | x[7]) == 0);
        int base = b * (2*ARITY) + 2*a;
        s_ri[t] = is64 ? x[2*base]     : x[base];
        s_vi[t] = is64 ? x[2*base + 2] : x[base + 1];
    }
    if (t < NF) { s_sum[t] = 0.f; s_sq[t] = 0.f; }
    __syncthreads();

    // ---- build A panel (32 rows x 224, hi+lo), swizzled ----
    for (int c = t; c < 896; c += 256) {
        int row = c / 28, s = c - row*28;
        int key = (row >> 1) & 3;
        int col = (s >> 2)*32 + ((s & 3) ^ key)*8;
        const float* rr = er + (size_t)s_ri[row] * EMB;
        const float* vr = ev + (size_t)s_vi[row] * EMB;
        int e0 = s*8;
        float4 v0 = ld4(rr, vr, e0);
        float4 v1 = ld4(rr, vr, e0 + 4);
        half8 hi, lo;
        hi[0]=(_Float16)v0.x; lo[0]=(_Float16)(v0.x-(float)hi[0]);
        hi[1]=(_Float16)v0.y; lo[1]=(_Float16)(v0.y-(float)hi[1]);
        hi[2]=(_Float16)v0.z; lo[2]=(_Float16)(v0.z-(float)hi[2]);
        hi[3]=(_Float16)v0.w; lo[3]=(_Float16)(v0.w-(float)hi[3]);
        hi[4]=(_Float16)v1.x; lo[4]=(_Float16)(v1.x-(float)hi[4]);
        hi[5]=(_Float16)v1.y; lo[5]=(_Float16)(v1.y-(float)hi[5]);
        hi[6]=(_Float16)v1.z; lo[6]=(_Float16)(v1.z-(float)hi[6]);
        hi[7]=(_Float16)v1.w; lo[7]=(_Float16)(v1.w-(float)hi[7]);
        *(half8*)&s_ahi[row*KP + col] = hi;
        *(half8*)&s_alo[row*KP + col] = lo;
    }
    __syncthreads();

    // ---- hoist A fragments (hi+lo x 7 ks) ----
    f32x4 ah[7], al[7];
    {
        int arow = wm*16 + cx;
        #pragma unroll
        for (int ks = 0; ks < 7; ++ks) {
            ah[ks] = *(const f32x4*)&s_ahi[arow*KP + ks*32 + rdsw];
            al[ks] = *(const f32x4*)&s_alo[arow*KP + ks*32 + rdsw];
        }
    }

    // ---- nf-streamed MFMA with register dbuf ----
    const _Float16* wbase = wT + (wn*7)*512 + cx*32 + q*8;

    #define LOADW(BH_, BL_, NF_) do {                                        \
        _Pragma("unroll")                                                    \
        for (int _k = 0; _k < 7; ++_k) {                                     \
            const _Float16* _p = wbase + _k*14336 + (NF_)*512;               \
            BH_[_k] = *(const f32x4*)_p;                                     \
            BL_[_k] = *(const f32x4*)(_p + 7168);                            \
        }                                                                    \
    } while (0)

    #define MFMAW(BH_, BL_, ACC_) do {                                       \
        ACC_ = (f32x4){0.f,0.f,0.f,0.f};                                     \
        _Pragma("unroll")                                                    \
        for (int _k = 0; _k < 7; ++_k) {                                     \
            ACC_ = __builtin_amdgcn_mfma_f32_16x16x32_f16(                   \
                __builtin_bit_cast(half8, ah[_k]),                           \
                __builtin_bit_cast(half8, BH_[_k]), ACC_, 0,0,0);            \
            ACC_ = __builtin_amdgcn_mfma_f32_16x16x32_f16(                   \
                __builtin_bit_cast(half8, ah[_k]),                           \
                __builtin_bit_cast(half8, BL_[_k]), ACC_, 0,0,0);            \
            ACC_ = __builtin_amdgcn_mfma_f32_16x16x32_f16(                   \
                __builtin_bit_cast(half8, al[_k]),                           \
                __builtin_bit_cast(half8, BH_[_k]), ACC_, 0,0,0);            \
        }                                                                    \
    } while (0)

    #define EPIW(ACC_, NF_) do {                                             \
        int _f = wn*112 + (NF_)*16 + cx;                                     \
        bool _valid = (_f < NF);                                             \
        float _bias = _valid ? cb[_f] : 0.f;                                 \
        float _ps = 0.f, _pq = 0.f;                                          \
        _Pragma("unroll")                                                    \
        for (int _r = 0; _r < 4; ++_r) {                                     \
            float _vv = ACC_[_r] + _bias;                                    \
            if (_valid) {                                                    \
                int _R = R0 + wm*16 + q*4 + _r;                              \
                m_raw[(size_t)_R*NF + _f] = (_Float16)_vv;                   \
                _ps += _vv; _pq += _vv*_vv;                                  \
            }                                                                \
        }                                                                    \
        _ps += __shfl_xor(_ps, 16); _ps += __shfl_xor(_ps, 32);              \
        _pq += __shfl_xor(_pq, 16); _pq += __shfl_xor(_pq, 32);              \
        if (_valid && q == 0) {                                              \
            atomicAdd(&s_sum[_f], _ps); atomicAdd(&s_sq[_f], _pq);           \
        }                                                                    \
    } while (0)

    f32x4 bh0[7], bl0[7], bh1[7], bl1[7];
    f32x4 accA, accB;

    LOADW(bh0, bl0, 0);
    LOADW(bh1, bl1, 1);
    MFMAW(bh0, bl0, accA);                                   // nf 0
    LOADW(bh0, bl0, 2); MFMAW(bh1, bl1, accB); EPIW(accA, 0);
    LOADW(bh1, bl1, 3); MFMAW(bh0, bl0, accA); EPIW(accB, 1);
    LOADW(bh0, bl0, 4); MFMAW(bh1, bl1, accB); EPIW(accA, 2);
    LOADW(bh1, bl1, 5); MFMAW(bh0, bl0, accA); EPIW(accB, 3);
    LOADW(bh0, bl0, 6); MFMAW(bh1, bl1, accB); EPIW(accA, 4);
    MFMAW(bh0, bl0, accA); EPIW(accB, 5);
    EPIW(accA, 6);

    __syncthreads();
    if (t < NF) {
        float* g = gshad + (blockIdx.x & 15) * 400;
        atomicAdd(&g[t], s_sum[t]);
        atomicAdd(&g[t + 200], s_sq[t]);
    }
}

// ---------------- k3: wave-autonomous MFMA, pipelined epilogue -------------
// (unchanged from round 14 -- passing at 46 us)
__launch_bounds__(256, 2)
__global__ void k3_mfma(const _Float16* __restrict__ m_raw,
                        const float* __restrict__ gshad,
                        const float* __restrict__ gamma,
                        const float* __restrict__ beta,
                        const _Float16* __restrict__ W_h,
                        const float* __restrict__ gb,
                        const float* __restrict__ fW,
                        float* __restrict__ out)
{
    __shared__ __align__(16) char smem[40192];
    float2* gbfw2 = (float2*)(smem + 28672);
    float*  scsh  = (float*)(smem + 28672 + 9728);

    const int t = threadIdx.x, lane = t & 63, wave = t >> 6;
    const int q = lane >> 4, cx = lane & 15;
    const int rdsw = (q ^ ((cx >> 1) & 3)) * 8;

    // ---- inlined BN finalize ----
    if (t < 224) {
        float sc = 0.f, sh = 0.f;
        if (t < NF) {
            float s = 0.f, qq = 0.f;
            #pragma unroll
            for (int c = 0; c < 16; ++c) { s += gshad[c*400 + t]; qq += gshad[c*400 + 200 + t]; }
            float inv = 1.0f / (float)NROWS;
            float mu  = s * inv;
            float var = qq * inv - mu*mu;
            float rs  = rsqrtf(var + BN_EPS);
            sc = rs * gamma[t];
            sh = beta[t] - mu*sc;
        }
        scsh[t] = sc; scsh[224 + t] = sh;
    }
    for (int i = t; i < 1216; i += 256) {
        float g = (i < FC) ? gb[i] : 0.f;
        float f = (i < FC) ? fW[i] : 0.f;
        gbfw2[i] = make_float2(g, f);
    }
    __syncthreads();

    // ---- build padded+swizzled A panel (64 rows x 224 f16) ----
    {
        _Float16* sa = (_Float16*)smem;
        for (int c = t; c < 1792; c += 256) {          // 64 rows x 28 chunks
            int Rp = c / 28, s = c - Rp*28;
            int a = Rp & 7, b = Rp >> 3;
            int key = (Rp >> 1) & 3;
            int col = (s >> 2)*32 + ((s & 3) ^ key)*8;
            half8 o;
            #pragma unroll
            for (int j = 0; j < 8; ++j) o[j] = (_Float16)0.f;
            if (a < ARITY && s < 25) {
                int R = (blockIdx.x*8 + b)*ARITY + a;
                half8 in = *(const half8*)&m_raw[(size_t)R*NF + s*8];
                #pragma unroll
                for (int j = 0; j < 8; ++j) {
                    int k = s*8 + j;
                    o[j] = (_Float16)fmaxf((float)in[j]*scsh[k] + scsh[224+k], 0.f);
                }
            } else if (a >= ARITY && s == 25) {
                o[0] = (_Float16)1.0f;                 // k==200 sentinel unit
            }
            *(half8*)&sa[Rp*KP + col] = o;
        }
    }
    __syncthreads();

    // ---- hoist A fragments (4 mf x 7 ks): rows mf*16+cx ----
    f32x4 av[4][7];
    {
        const _Float16* sa = (const _Float16*)smem;
        #pragma unroll
        for (int mf = 0; mf < 4; ++mf) {
            int row = mf*16 + cx;
            #pragma unroll
            for (int ks = 0; ks < 7; ++ks)
                av[mf][ks] = *(const f32x4*)&sa[row*KP + ks*32 + rdsw];
        }
    }

    // ---- per-wave o-quarter, coalesced B direct to regs ----
    const int nbase = wave * (NPAD/4);                 // 608 N-rows per wave
    const char* wsrc = (const char*)W_h + (size_t)nbase * 448;  // tile-major
    const int boff = cx*64 + q*16;                     // within-1KB lane offset

    #define LOADT(BV_, NT_) do {                                             \
        const char* _b = wsrc + (size_t)(NT_)*7168 + boff;                   \
        _Pragma("unroll")                                                    \
        for (int _k = 0; _k < 7; ++_k)                                       \
            BV_[_k] = *(const f32x4*)(_b + _k*1024);                         \
    } while (0)

    #define MFMAT(BV_, ACC_) do {                                            \
        _Pragma("unroll")                                                    \
        for (int _m = 0; _m < 4; ++_m) ACC_[_m] = (f32x4){0.f,0.f,0.f,0.f};  \
        _Pragma("unroll")                                                    \
        for (int _k = 0; _k < 7; ++_k) {                                     \
            _Pragma("unroll")                                                \
            for (int _m = 0; _m < 4; ++_m)                                   \
                ACC_[_m] = __builtin_amdgcn_mfma_f32_16x16x32_f16(           \
                    __builtin_bit_cast(half8, av[_m][_k]),                   \
                    __builtin_bit_cast(half8, BV_[_k]), ACC_[_m], 0, 0, 0);  \
        }                                                                    \
    } while (0)

    float preg[4] = {0.f, 0.f, 0.f, 0.f};

    #define EPI(ACC_, NT_) do {                                              \
        float2 _gf = gbfw2[(nbase + (NT_)*16 + cx) >> 1];                    \
        _Pragma("unroll")                                                    \
        for (int _m = 0; _m < 4; ++_m) {                                     \
            f32x4 _a4 = ACC_[_m];                                            \
            float _v = fminf(fminf(_a4[0], _a4[1]), fminf(_a4[2], _a4[3]));  \
            _v = fminf(_v, __shfl_xor(_v, 16));     /* 8-row batch min */    \
            float _vp = _v + __shfl_xor(_v, 1);     /* A + C halves */       \
            float _val = fmaxf(_vp + _gf.x, 0.f) * _gf.y;                    \
            if (((q & 1) == 0) && ((cx & 1) == 0)) preg[_m] += _val;         \
        }                                                                    \
    } while (0)

    f32x4 bv0[7], bv1[7];
    f32x4 acc0[4], acc1[4];

    LOADT(bv0, 0);
    LOADT(bv1, 1);
    MFMAT(bv0, acc0);                       // tile 0
    // steps nt = 1..34 (17 pairs): LOAD(nt+1) | MFMA(nt) | EPI(nt-1)
    for (int k = 0; k < 17; ++k) {
        int nt = 2*k + 1;
        LOADT(bv0, nt + 1); MFMAT(bv1, acc1); EPI(acc0, nt - 1);
        LOADT(bv1, nt + 2); MFMAT(bv0, acc0); EPI(acc1, nt);
    }
    // tail: nt = 35, 36, 37
    LOADT(bv0, 36); MFMAT(bv1, acc1); EPI(acc0, 34);
    LOADT(bv1, 37); MFMAT(bv0, acc0); EPI(acc1, 35);
    MFMAT(bv1, acc1); EPI(acc0, 36);
    EPI(acc1, 37);

    #pragma unroll
    for (int mf = 0; mf < 4; ++mf) {
        float v = preg[mf];
        v += __shfl_xor(v, 2);
        v += __shfl_xor(v, 4);
        v += __shfl_xor(v, 8);
        if (cx == 0 && (q & 1) == 0) {
            int bb = blockIdx.x*8 + mf*2 + (q >> 1);
            atomicAdd(&out[bb], v);
        }
    }
}

extern "C" void kernel_launch(void* const* d_in, const int* in_sizes, int n_in,
                              void* d_out, int out_size, void* d_ws, size_t ws_size,
                              hipStream_t stream)
{
    const int*   x   = (const int*)  d_in[0];
    const float* er  = (const float*)d_in[1];
    const float* ev  = (const float*)d_in[2];
    const float* cw  = (const float*)d_in[3];
    const float* cb  = (const float*)d_in[4];
    const float* gam = (const float*)d_in[5];
    const float* bet = (const float*)d_in[6];
    const float* gW  = (const float*)d_in[7];
    const float* gb  = (const float*)d_in[8];
    const float* fW  = (const float*)d_in[9];
    const float* fb  = (const float*)d_in[10];

    float* ws = (float*)d_ws;
    _Float16* m_raw = (_Float16*)(ws + MRAW_OFF);
    _Float16* W_h   = (_Float16*)(ws + WH_OFF);
    _Float16* wT    = (_Float16*)(ws + WT_OFF);
    float* gshad    = ws + STAT_OFF;
    float* out      = (float*)d_out;

    (void)hipMemsetAsync(gshad, 0, 16*400*sizeof(float), stream);

    k0_prep<<<(K0_TOT + 255)/256, 256, 0, stream>>>(cw, gW, fb, wT, W_h, out);
    k1_mfma<<<NROWS/32, 256, 0, stream>>>(x, er, ev, wT, cb, m_raw, gshad);
    k3_mfma<<<MPAD/64, 256, 0, stream>>>(m_raw, gshad, gam, bet, W_h, gb, fW, out);
}

// Round 16
// 73.802 us; speedup vs baseline: 1.1783x; 1.1783x over previous
//
#include <hip/hip_runtime.h>
#include <hip/hip_bf16.h>
#include <hip/hip_fp16.h>

#define B_    4096
#define ARITY 6
#define EMB   100
#define NF    200
#define FC    1200
#define NROWS (B_*ARITY)      // 24576
#define MPAD  (B_*8)          // 32768 padded M rows (8 per batch, 2 sentinel)
#define NPAD  2432            // N rows of W_h (A/C pairs interleaved)
#define BN_EPS 1e-5f
#define KP    224
#define SENT  32768.0f
#define NTW   (NPAD/4/16)     // 38 tiles of 16 N-rows per wave (o-quarter)

typedef _Float16 half8 __attribute__((ext_vector_type(8)));
typedef float f32x4 __attribute__((ext_vector_type(4)));

// ws float offsets
#define MRAW_OFF 0              // m_raw f16 [24576][200] -> 2,457,600 f
#define WH_OFF   2457600        // W_h f16, tile-major coalesced (k3) -> 272,384 f
#define WT_OFF   2729984        // wT  f16 [ks][hi|lo][224][32] swizzled (k1) -> 50,176 f
#define STAT_OFF 2780160        // gshad[16][400]

__device__ __forceinline__ void gload16(const void* g, void* l) {
    __builtin_amdgcn_global_load_lds(
        (const __attribute__((address_space(1))) void*)g,
        (__attribute__((address_space(3))) void*)l, 16, 0, 0);
}

__device__ __forceinline__ float4 ld4(const float* rr, const float* vr, int e) {
    if (e < EMB)        return *(const float4*)&rr[e];
    else if (e < 2*EMB) return *(const float4*)&vr[e - EMB];
    float4 z = {0.f,0.f,0.f,0.f}; return z;
}

// ---------------- k0: weight prep + out init + gshad zero ------------------
// wT (k1, LDS-staged): off = ks*14336 + f*32 + ((ls^key)*8), key=(f>>1)&3,
//   hi at +0, lo at +7168  (round-10 layout, matches k1's rdsw ds_read).
// W_h (k3, direct-load): off = (n>>4)*3584 + (s>>2)*512 + (n&15)*32 + (s&3)*8
//   (tile-major: each wave-load instruction reads 1KB contiguous).
#define K0_W1 (224*28)
#define K0_W2 (K0_W1 + NPAD*28)
#define K0_W3 (K0_W2 + B_)
#define K0_TOT (K0_W3 + 6400)
__launch_bounds__(256)
__global__ void k0_prep(const float* __restrict__ cw, const float* __restrict__ gW,
                        const float* __restrict__ fb,
                        _Float16* __restrict__ wT,
                        _Float16* __restrict__ W_h, float* __restrict__ out,
                        float* __restrict__ gshad)
{
    int id = blockIdx.x * 256 + threadIdx.x;
    if (id < K0_W1) {
        int f = id / 28, s = id - f*28;
        int ks = s >> 2, ls = s & 3, key = (f >> 1) & 3;
        int off = ks*14336 + f*32 + ((ls ^ key)*8);
        half8 h, l;
        #pragma unroll
        for (int j = 0; j < 8; ++j) {
            int k = s*8 + j;
            float v = (f < NF && k < NF) ? cw[f*NF + k] : 0.f;
            _Float16 hi = (_Float16)v;
            h[j] = hi; l[j] = (_Float16)(v - (float)hi);
        }
        *(half8*)&wT[off] = h;
        *(half8*)&wT[off + 7168] = l;
    } else if (id < K0_W2) {
        int id2 = id - K0_W1;
        int n = id2 / 28, s = id2 - n*28;
        int o = n >> 1, hf = n & 1;
        int off = (n >> 4)*3584 + (s >> 2)*512 + (n & 15)*32 + (s & 3)*8;
        half8 h;
        #pragma unroll
        for (int j = 0; j < 8; ++j) {
            int k = s*8 + j;
            float v = 0.f;
            if (k < NF && n < 2*FC) v = gW[(size_t)o*400 + hf*200 + k];
            if (k == NF) v = SENT;           // sentinel column
            h[j] = (_Float16)v;
        }
        *(half8*)&W_h[off] = h;
    } else if (id < K0_W3) {
        out[id - K0_W2] = fb[0];
    } else if (id < K0_TOT) {
        gshad[id - K0_W3] = 0.f;             // replaces hipMemsetAsync
    }
}

// ---------------- k1: gather + split-f16 MFMA conv + stats -----------------
// (round-10 version verbatim -- fenced ring-2 LDS staging; rest=31.5us best)
__launch_bounds__(256)
__global__ void k1_mfma(const int* __restrict__ x,
                        const float* __restrict__ er,
                        const float* __restrict__ ev,
                        const _Float16* __restrict__ wT,
                        const float* __restrict__ cb,
                        _Float16* __restrict__ m_raw,
                        float* __restrict__ gshad)
{
    __shared__ __align__(16) char smem[59200];
    float* s_sum = (float*)(smem + 57344);
    float* s_sq  = (float*)(smem + 58144);
    int*   s_ri  = (int*)(smem + 58944);
    int*   s_vi  = (int*)(smem + 59072);

    const int t = threadIdx.x, lane = t & 63, wave = t >> 6;
    const int wm = wave >> 1, wn = wave & 1;
    const int R0 = blockIdx.x * 32;
    const int q = lane >> 4, cx = lane & 15;
    const int rdsw = (q ^ ((cx >> 1) & 3)) * 8;

    if (t < 32) {
        int R = R0 + t, b = R / ARITY, a = R - b * ARITY;
        bool is64 = ((x[1] | x[3] | x[5] | x[7]) == 0);
        int base = b * (2*ARITY) + 2*a;
        s_ri[t] = is64 ? x[2*base]     : x[base];
        s_vi[t] = is64 ? x[2*base + 2] : x[base + 1];
    }
    if (t < NF) { s_sum[t] = 0.f; s_sq[t] = 0.f; }
    __syncthreads();

    // ---- build A panel (32 rows x 224, hi+lo) in buf0, swizzled ----
    {
        _Float16* s_ahi = (_Float16*)smem;          // 32x224
        _Float16* s_alo = s_ahi + 7168;
        for (int c = t; c < 896; c += 256) {
            int row = c / 28, s = c - row*28;
            int key = (row >> 1) & 3;
            int col = (s >> 2)*32 + ((s & 3) ^ key)*8;
            const float* rr = er + (size_t)s_ri[row] * EMB;
            const float* vr = ev + (size_t)s_vi[row] * EMB;
            int e0 = s*8;
            float4 v0 = ld4(rr, vr, e0);
            float4 v1 = ld4(rr, vr, e0 + 4);
            half8 hi, lo;
            hi[0]=(_Float16)v0.x; lo[0]=(_Float16)(v0.x-(float)hi[0]);
            hi[1]=(_Float16)v0.y; lo[1]=(_Float16)(v0.y-(float)hi[1]);
            hi[2]=(_Float16)v0.z; lo[2]=(_Float16)(v0.z-(float)hi[2]);
            hi[3]=(_Float16)v0.w; lo[3]=(_Float16)(v0.w-(float)hi[3]);
            hi[4]=(_Float16)v1.x; lo[4]=(_Float16)(v1.x-(float)hi[4]);
            hi[5]=(_Float16)v1.y; lo[5]=(_Float16)(v1.y-(float)hi[5]);
            hi[6]=(_Float16)v1.z; lo[6]=(_Float16)(v1.z-(float)hi[6]);
            hi[7]=(_Float16)v1.w; lo[7]=(_Float16)(v1.w-(float)hi[7]);
            *(half8*)&s_ahi[row*KP + col] = hi;
            *(half8*)&s_alo[row*KP + col] = lo;
        }
    }
    __syncthreads();

    // ---- hoist A fragments (1 mf x 7 ks, hi+lo) to registers ----
    f32x4 ah[7], al[7];
    {
        const _Float16* s_ahi = (const _Float16*)smem;
        const _Float16* s_alo = s_ahi + 7168;
        int arow = wm*16 + cx;
        #pragma unroll
        for (int ks = 0; ks < 7; ++ks) {
            ah[ks] = *(const f32x4*)&s_ahi[arow*KP + ks*32 + rdsw];
            al[ks] = *(const f32x4*)&s_alo[arow*KP + ks*32 + rdsw];
            asm volatile("" : "+v"(ah[ks]), "+v"(al[ks]));
        }
    }
    __syncthreads();   // A reads done; drains all vmem -> counts exact below

    #define STAGE_W(KS_, BUF_) do {                                          \
        const char* _src = (const char*)wT + (size_t)(KS_) * 28672;          \
        char* _dst = smem + (BUF_) * 28672;                                  \
        _Pragma("unroll")                                                    \
        for (int _i = 0; _i < 7; ++_i) {                                     \
            int _j = wave + 4*_i;                                            \
            gload16(_src + (size_t)(_j*64 + lane)*16, _dst + _j*1024);       \
        }                                                                    \
    } while (0)

    STAGE_W(0, 0);
    STAGE_W(1, 1);

    f32x4 acc[7];
    #pragma unroll
    for (int nf = 0; nf < 7; ++nf) acc[nf] = (f32x4){0.f,0.f,0.f,0.f};

    for (int ks = 0; ks < 7; ++ks) {
        if (ks < 6) asm volatile("s_waitcnt vmcnt(7)" ::: "memory");
        else        asm volatile("s_waitcnt vmcnt(0)" ::: "memory");
        __builtin_amdgcn_s_barrier();
        __builtin_amdgcn_sched_barrier(0);

        const _Float16* wb = (const _Float16*)(smem + (ks & 1) * 28672);
        #pragma unroll
        for (int nf = 0; nf < 7; ++nf) {
            int rb = (wn*112 + nf*16 + cx)*32 + rdsw;
            half8 bh = *(const half8*)&wb[rb];
            half8 bl = *(const half8*)&wb[7168 + rb];
            acc[nf] = __builtin_amdgcn_mfma_f32_16x16x32_f16(
                __builtin_bit_cast(half8, ah[ks]), bh, acc[nf], 0,0,0);
            acc[nf] = __builtin_amdgcn_mfma_f32_16x16x32_f16(
                __builtin_bit_cast(half8, ah[ks]), bl, acc[nf], 0,0,0);
            acc[nf] = __builtin_amdgcn_mfma_f32_16x16x32_f16(
                __builtin_bit_cast(half8, al[ks]), bh, acc[nf], 0,0,0);
        }
        // FENCE: own ds_reads complete, all waves past them, nothing moves
        // across -- only then may the stage overwrite this buffer.
        asm volatile("s_waitcnt lgkmcnt(0)" ::: "memory");
        __builtin_amdgcn_sched_barrier(0);
        __builtin_amdgcn_s_barrier();
        __builtin_amdgcn_sched_barrier(0);
        if (ks + 2 < 7) STAGE_W(ks + 2, ks & 1);
    }

    // epilogue: +bias, write m_raw (f16), block stats
    #pragma unroll
    for (int nf = 0; nf < 7; ++nf) {
        int f = wn*112 + nf*16 + cx;
        bool valid = (f < NF);
        float bias = valid ? cb[f] : 0.f;
        float ps = 0.f, pq = 0.f;
        #pragma unroll
        for (int reg = 0; reg < 4; ++reg) {
            float vv = acc[nf][reg] + bias;
            if (valid) {
                int R = R0 + wm*16 + q*4 + reg;
                m_raw[(size_t)R*NF + f] = (_Float16)vv;
                ps += vv; pq += vv*vv;
            }
        }
        ps += __shfl_xor(ps, 16); ps += __shfl_xor(ps, 32);
        pq += __shfl_xor(pq, 16); pq += __shfl_xor(pq, 32);
        if (valid && q == 0) { atomicAdd(&s_sum[f], ps); atomicAdd(&s_sq[f], pq); }
    }
    __syncthreads();
    if (t < NF) {
        float* g = gshad + (blockIdx.x & 15) * 400;
        atomicAdd(&g[t], s_sum[t]);
        atomicAdd(&g[t + 200], s_sq[t]);
    }
}

// ---------------- k3: wave-autonomous MFMA, pipelined epilogue -------------
// (round-14 version verbatim -- passing at 46 us)
__launch_bounds__(256, 2)
__global__ void k3_mfma(const _Float16* __restrict__ m_raw,
                        const float* __restrict__ gshad,
                        const float* __restrict__ gamma,
                        const float* __restrict__ beta,
                        const _Float16* __restrict__ W_h,
                        const float* __restrict__ gb,
                        const float* __restrict__ fW,
                        float* __restrict__ out)
{
    __shared__ __align__(16) char smem[40192];
    float2* gbfw2 = (float2*)(smem + 28672);
    float*  scsh  = (float*)(smem + 28672 + 9728);

    const int t = threadIdx.x, lane = t & 63, wave = t >> 6;
    const int q = lane >> 4, cx = lane & 15;
    const int rdsw = (q ^ ((cx >> 1) & 3)) * 8;

    // ---- inlined BN finalize ----
    if (t < 224) {
        float sc = 0.f, sh = 0.f;
        if (t < NF) {
            float s = 0.f, qq = 0.f;
            #pragma unroll
            for (int c = 0; c < 16; ++c) { s += gshad[c*400 + t]; qq += gshad[c*400 + 200 + t]; }
            float inv = 1.0f / (float)NROWS;
            float mu  = s * inv;
            float var = qq * inv - mu*mu;
            float rs  = rsqrtf(var + BN_EPS);
            sc = rs * gamma[t];
            sh = beta[t] - mu*sc;
        }
        scsh[t] = sc; scsh[224 + t] = sh;
    }
    for (int i = t; i < 1216; i += 256) {
        float g = (i < FC) ? gb[i] : 0.f;
        float f = (i < FC) ? fW[i] : 0.f;
        gbfw2[i] = make_float2(g, f);
    }
    __syncthreads();

    // ---- build padded+swizzled A panel (64 rows x 224 f16) ----
    {
        _Float16* sa = (_Float16*)smem;
        for (int c = t; c < 1792; c += 256) {          // 64 rows x 28 chunks
            int Rp = c / 28, s = c - Rp*28;
            int a = Rp & 7, b = Rp >> 3;
            int key = (Rp >> 1) & 3;
            int col = (s >> 2)*32 + ((s & 3) ^ key)*8;
            half8 o;
            #pragma unroll
            for (int j = 0; j < 8; ++j) o[j] = (_Float16)0.f;
            if (a < ARITY && s < 25) {
                int R = (blockIdx.x*8 + b)*ARITY + a;
                half8 in = *(const half8*)&m_raw[(size_t)R*NF + s*8];
                #pragma unroll
                for (int j = 0; j < 8; ++j) {
                    int k = s*8 + j;
                    o[j] = (_Float16)fmaxf((float)in[j]*scsh[k] + scsh[224+k], 0.f);
                }
            } else if (a >= ARITY && s == 25) {
                o[0] = (_Float16)1.0f;                 // k==200 sentinel unit
            }
            *(half8*)&sa[Rp*KP + col] = o;
        }
    }
    __syncthreads();

    // ---- hoist A fragments (4 mf x 7 ks): rows mf*16+cx ----
    f32x4 av[4][7];
    {
        const _Float16* sa = (const _Float16*)smem;
        #pragma unroll
        for (int mf = 0; mf < 4; ++mf) {
            int row = mf*16 + cx;
            #pragma unroll
            for (int ks = 0; ks < 7; ++ks)
                av[mf][ks] = *(const f32x4*)&sa[row*KP + ks*32 + rdsw];
        }
    }

    // ---- per-wave o-quarter, coalesced B direct to regs ----
    const int nbase = wave * (NPAD/4);                 // 608 N-rows per wave
    const char* wsrc = (const char*)W_h + (size_t)nbase * 448;  // tile-major
    const int boff = cx*64 + q*16;                     // within-1KB lane offset

    #define LOADT(BV_, NT_) do {                                             \
        const char* _b = wsrc + (size_t)(NT_)*7168 + boff;                   \
        _Pragma("unroll")                                                    \
        for (int _k = 0; _k < 7; ++_k)                                       \
            BV_[_k] = *(const f32x4*)(_b + _k*1024);                         \
    } while (0)

    #define MFMAT(BV_, ACC_) do {                                            \
        _Pragma("unroll")                                                    \
        for (int _m = 0; _m < 4; ++_m) ACC_[_m] = (f32x4){0.f,0.f,0.f,0.f};  \
        _Pragma("unroll")                                                    \
        for (int _k = 0; _k < 7; ++_k) {                                     \
            _Pragma("unroll")                                                \
            for (int _m = 0; _m < 4; ++_m)                                   \
                ACC_[_m] = __builtin_amdgcn_mfma_f32_16x16x32_f16(           \
                    __builtin_bit_cast(half8, av[_m][_k]),                   \
                    __builtin_bit_cast(half8, BV_[_k]), ACC_[_m], 0, 0, 0);  \
        }                                                                    \
    } while (0)

    float preg[4] = {0.f, 0.f, 0.f, 0.f};

    #define EPI(ACC_, NT_) do {                                              \
        float2 _gf = gbfw2[(nbase + (NT_)*16 + cx) >> 1];                    \
        _Pragma("unroll")                                                    \
        for (int _m = 0; _m < 4; ++_m) {                                     \
            f32x4 _a4 = ACC_[_m];                                            \
            float _v = fminf(fminf(_a4[0], _a4[1]), fminf(_a4[2], _a4[3]));  \
            _v = fminf(_v, __shfl_xor(_v, 16));     /* 8-row batch min */    \
            float _vp = _v + __shfl_xor(_v, 1);     /* A + C halves */       \
            float _val = fmaxf(_vp + _gf.x, 0.f) * _gf.y;                    \
            if (((q & 1) == 0) && ((cx & 1) == 0)) preg[_m] += _val;         \
        }                                                                    \
    } while (0)

    f32x4 bv0[7], bv1[7];
    f32x4 acc0[4], acc1[4];

    LOADT(bv0, 0);
    LOADT(bv1, 1);
    MFMAT(bv0, acc0);                       // tile 0
    // steps nt = 1..34 (17 pairs): LOAD(nt+1) | MFMA(nt) | EPI(nt-1)
    for (int k = 0; k < 17; ++k) {
        int nt = 2*k + 1;
        LOADT(bv0, nt + 1); MFMAT(bv1, acc1); EPI(acc0, nt - 1);
        LOADT(bv1, nt + 2); MFMAT(bv0, acc0); EPI(acc1, nt);
    }
    // tail: nt = 35, 36, 37
    LOADT(bv0, 36); MFMAT(bv1, acc1); EPI(acc0, 34);
    LOADT(bv1, 37); MFMAT(bv0, acc0); EPI(acc1, 35);
    MFMAT(bv1, acc1); EPI(acc0, 36);
    EPI(acc1, 37);

    #pragma unroll
    for (int mf = 0; mf < 4; ++mf) {
        float v = preg[mf];
        v += __shfl_xor(v, 2);
        v += __shfl_xor(v, 4);
        v += __shfl_xor(v, 8);
        if (cx == 0 && (q & 1) == 0) {
            int bb = blockIdx.x*8 + mf*2 + (q >> 1);
            atomicAdd(&out[bb], v);
        }
    }
}

extern "C" void kernel_launch(void* const* d_in, const int* in_sizes, int n_in,
                              void* d_out, int out_size, void* d_ws, size_t ws_size,
                              hipStream_t stream)
{
    const int*   x   = (const int*)  d_in[0];
    const float* er  = (const float*)d_in[1];
    const float* ev  = (const float*)d_in[2];
    const float* cw  = (const float*)d_in[3];
    const float* cb  = (const float*)d_in[4];
    const float* gam = (const float*)d_in[5];
    const float* bet = (const float*)d_in[6];
    const float* gW  = (const float*)d_in[7];
    const float* gb  = (const float*)d_in[8];
    const float* fW  = (const float*)d_in[9];
    const float* fb  = (const float*)d_in[10];

    float* ws = (float*)d_ws;
    _Float16* m_raw = (_Float16*)(ws + MRAW_OFF);
    _Float16* W_h   = (_Float16*)(ws + WH_OFF);
    _Float16* wT    = (_Float16*)(ws + WT_OFF);
    float* gshad    = ws + STAT_OFF;
    float* out      = (float*)d_out;

    k0_prep<<<(K0_TOT + 255)/256, 256, 0, stream>>>(cw, gW, fb, wT, W_h, out, gshad);
    k1_mfma<<<NROWS/32, 256, 0, stream>>>(x, er, ev, wT, cb, m_raw, gshad);
    k3_mfma<<<MPAD/64, 256, 0, stream>>>(m_raw, gshad, gam, bet, W_h, gb, fW, out);
}

// Round 17
// 71.770 us; speedup vs baseline: 1.2117x; 1.0283x over previous
//
#include <hip/hip_runtime.h>
#include <hip/hip_bf16.h>
#include <hip/hip_fp16.h>

#define B_    4096
#define ARITY 6
#define EMB   100
#define NF    200
#define FC    1200
#define NROWS (B_*ARITY)      // 24576
#define NPAD  2432            // N rows of W_h (A/C pairs interleaved)
#define BN_EPS 1e-5f
#define KP    224
#define SENT  32768.0f
#define NTW   (NPAD/4/16)     // 38 tiles of 16 N-rows per wave (o-quarter)

typedef _Float16 half8 __attribute__((ext_vector_type(8)));
typedef float f32x4 __attribute__((ext_vector_type(4)));

// ws float offsets
#define MRAW_OFF 0              // m_raw f16 [24576][200] -> 2,457,600 f
#define WH_OFF   2457600        // W_h f16, tile-major coalesced (k3) -> 272,384 f
#define WT_OFF   2729984        // wT  f16 [ks][hi|lo][224][32] swizzled (k1) -> 50,176 f
#define STAT_OFF 2780160        // gshad[16][400]

__device__ __forceinline__ void gload16(const void* g, void* l) {
    __builtin_amdgcn_global_load_lds(
        (const __attribute__((address_space(1))) void*)g,
        (__attribute__((address_space(3))) void*)l, 16, 0, 0);
}

__device__ __forceinline__ float4 ld4(const float* rr, const float* vr, int e) {
    if (e < EMB)        return *(const float4*)&rr[e];
    else if (e < 2*EMB) return *(const float4*)&vr[e - EMB];
    float4 z = {0.f,0.f,0.f,0.f}; return z;
}

// ---------------- k0: weight prep + out init + gshad zero ------------------
// (byte-identical to round 16)
#define K0_W1 (224*28)
#define K0_W2 (K0_W1 + NPAD*28)
#define K0_W3 (K0_W2 + B_)
#define K0_TOT (K0_W3 + 6400)
__launch_bounds__(256)
__global__ void k0_prep(const float* __restrict__ cw, const float* __restrict__ gW,
                        const float* __restrict__ fb,
                        _Float16* __restrict__ wT,
                        _Float16* __restrict__ W_h, float* __restrict__ out,
                        float* __restrict__ gshad)
{
    int id = blockIdx.x * 256 + threadIdx.x;
    if (id < K0_W1) {
        int f = id / 28, s = id - f*28;
        int ks = s >> 2, ls = s & 3, key = (f >> 1) & 3;
        int off = ks*14336 + f*32 + ((ls ^ key)*8);
        half8 h, l;
        #pragma unroll
        for (int j = 0; j < 8; ++j) {
            int k = s*8 + j;
            float v = (f < NF && k < NF) ? cw[f*NF + k] : 0.f;
            _Float16 hi = (_Float16)v;
            h[j] = hi; l[j] = (_Float16)(v - (float)hi);
        }
        *(half8*)&wT[off] = h;
        *(half8*)&wT[off + 7168] = l;
    } else if (id < K0_W2) {
        int id2 = id - K0_W1;
        int n = id2 / 28, s = id2 - n*28;
        int o = n >> 1, hf = n & 1;
        int off = (n >> 4)*3584 + (s >> 2)*512 + (n & 15)*32 + (s & 3)*8;
        half8 h;
        #pragma unroll
        for (int j = 0; j < 8; ++j) {
            int k = s*8 + j;
            float v = 0.f;
            if (k < NF && n < 2*FC) v = gW[(size_t)o*400 + hf*200 + k];
            if (k == NF) v = SENT;           // sentinel column (harmless now)
            h[j] = (_Float16)v;
        }
        *(half8*)&W_h[off] = h;
    } else if (id < K0_W3) {
        out[id - K0_W2] = fb[0];
    } else if (id < K0_TOT) {
        gshad[id - K0_W3] = 0.f;
    }
}

// ---------------- k1: gather + split-f16 MFMA conv + stats -----------------
// (byte-identical to round 16 -- fenced ring-2 LDS staging)
__launch_bounds__(256)
__global__ void k1_mfma(const int* __restrict__ x,
                        const float* __restrict__ er,
                        const float* __restrict__ ev,
                        const _Float16* __restrict__ wT,
                        const float* __restrict__ cb,
                        _Float16* __restrict__ m_raw,
                        float* __restrict__ gshad)
{
    __shared__ __align__(16) char smem[59200];
    float* s_sum = (float*)(smem + 57344);
    float* s_sq  = (float*)(smem + 58144);
    int*   s_ri  = (int*)(smem + 58944);
    int*   s_vi  = (int*)(smem + 59072);

    const int t = threadIdx.x, lane = t & 63, wave = t >> 6;
    const int wm = wave >> 1, wn = wave & 1;
    const int R0 = blockIdx.x * 32;
    const int q = lane >> 4, cx = lane & 15;
    const int rdsw = (q ^ ((cx >> 1) & 3)) * 8;

    if (t < 32) {
        int R = R0 + t, b = R / ARITY, a = R - b * ARITY;
        bool is64 = ((x[1] | x[3] | x[5] | x[7]) == 0);
        int base = b * (2*ARITY) + 2*a;
        s_ri[t] = is64 ? x[2*base]     : x[base];
        s_vi[t] = is64 ? x[2*base + 2] : x[base + 1];
    }
    if (t < NF) { s_sum[t] = 0.f; s_sq[t] = 0.f; }
    __syncthreads();

    {
        _Float16* s_ahi = (_Float16*)smem;          // 32x224
        _Float16* s_alo = s_ahi + 7168;
        for (int c = t; c < 896; c += 256) {
            int row = c / 28, s = c - row*28;
            int key = (row >> 1) & 3;
            int col = (s >> 2)*32 + ((s & 3) ^ key)*8;
            const float* rr = er + (size_t)s_ri[row] * EMB;
            const float* vr = ev + (size_t)s_vi[row] * EMB;
            int e0 = s*8;
            float4 v0 = ld4(rr, vr, e0);
            float4 v1 = ld4(rr, vr, e0 + 4);
            half8 hi, lo;
            hi[0]=(_Float16)v0.x; lo[0]=(_Float16)(v0.x-(float)hi[0]);
            hi[1]=(_Float16)v0.y; lo[1]=(_Float16)(v0.y-(float)hi[1]);
            hi[2]=(_Float16)v0.z; lo[2]=(_Float16)(v0.z-(float)hi[2]);
            hi[3]=(_Float16)v0.w; lo[3]=(_Float16)(v0.w-(float)hi[3]);
            hi[4]=(_Float16)v1.x; lo[4]=(_Float16)(v1.x-(float)hi[4]);
            hi[5]=(_Float16)v1.y; lo[5]=(_Float16)(v1.y-(float)hi[5]);
            hi[6]=(_Float16)v1.z; lo[6]=(_Float16)(v1.z-(float)hi[6]);
            hi[7]=(_Float16)v1.w; lo[7]=(_Float16)(v1.w-(float)hi[7]);
            *(half8*)&s_ahi[row*KP + col] = hi;
            *(half8*)&s_alo[row*KP + col] = lo;
        }
    }
    __syncthreads();

    f32x4 ah[7], al[7];
    {
        const _Float16* s_ahi = (const _Float16*)smem;
        const _Float16* s_alo = s_ahi + 7168;
        int arow = wm*16 + cx;
        #pragma unroll
        for (int ks = 0; ks < 7; ++ks) {
            ah[ks] = *(const f32x4*)&s_ahi[arow*KP + ks*32 + rdsw];
            al[ks] = *(const f32x4*)&s_alo[arow*KP + ks*32 + rdsw];
            asm volatile("" : "+v"(ah[ks]), "+v"(al[ks]));
        }
    }
    __syncthreads();

    #define STAGE_W(KS_, BUF_) do {                                          \
        const char* _src = (const char*)wT + (size_t)(KS_) * 28672;          \
        char* _dst = smem + (BUF_) * 28672;                                  \
        _Pragma("unroll")                                                    \
        for (int _i = 0; _i < 7; ++_i) {                                     \
            int _j = wave + 4*_i;                                            \
            gload16(_src + (size_t)(_j*64 + lane)*16, _dst + _j*1024);       \
        }                                                                    \
    } while (0)

    STAGE_W(0, 0);
    STAGE_W(1, 1);

    f32x4 acc[7];
    #pragma unroll
    for (int nf = 0; nf < 7; ++nf) acc[nf] = (f32x4){0.f,0.f,0.f,0.f};

    for (int ks = 0; ks < 7; ++ks) {
        if (ks < 6) asm volatile("s_waitcnt vmcnt(7)" ::: "memory");
        else        asm volatile("s_waitcnt vmcnt(0)" ::: "memory");
        __builtin_amdgcn_s_barrier();
        __builtin_amdgcn_sched_barrier(0);

        const _Float16* wb = (const _Float16*)(smem + (ks & 1) * 28672);
        #pragma unroll
        for (int nf = 0; nf < 7; ++nf) {
            int rb = (wn*112 + nf*16 + cx)*32 + rdsw;
            half8 bh = *(const half8*)&wb[rb];
            half8 bl = *(const half8*)&wb[7168 + rb];
            acc[nf] = __builtin_amdgcn_mfma_f32_16x16x32_f16(
                __builtin_bit_cast(half8, ah[ks]), bh, acc[nf], 0,0,0);
            acc[nf] = __builtin_amdgcn_mfma_f32_16x16x32_f16(
                __builtin_bit_cast(half8, ah[ks]), bl, acc[nf], 0,0,0);
            acc[nf] = __builtin_amdgcn_mfma_f32_16x16x32_f16(
                __builtin_bit_cast(half8, al[ks]), bh, acc[nf], 0,0,0);
        }
        asm volatile("s_waitcnt lgkmcnt(0)" ::: "memory");
        __builtin_amdgcn_sched_barrier(0);
        __builtin_amdgcn_s_barrier();
        __builtin_amdgcn_sched_barrier(0);
        if (ks + 2 < 7) STAGE_W(ks + 2, ks & 1);
    }

    #pragma unroll
    for (int nf = 0; nf < 7; ++nf) {
        int f = wn*112 + nf*16 + cx;
        bool valid = (f < NF);
        float bias = valid ? cb[f] : 0.f;
        float ps = 0.f, pq = 0.f;
        #pragma unroll
        for (int reg = 0; reg < 4; ++reg) {
            float vv = acc[nf][reg] + bias;
            if (valid) {
                int R = R0 + wm*16 + q*4 + reg;
                m_raw[(size_t)R*NF + f] = (_Float16)vv;
                ps += vv; pq += vv*vv;
            }
        }
        ps += __shfl_xor(ps, 16); ps += __shfl_xor(ps, 32);
        pq += __shfl_xor(pq, 16); pq += __shfl_xor(pq, 32);
        if (valid && q == 0) { atomicAdd(&s_sum[f], ps); atomicAdd(&s_sq[f], pq); }
    }
    __syncthreads();
    if (t < NF) {
        float* g = gshad + (blockIdx.x & 15) * 400;
        atomicAdd(&g[t], s_sum[t]);
        atomicAdd(&g[t + 200], s_sq[t]);
    }
}

// ---------------- k3: 48 real rows/block (NO pad rows), 3-frag wave tile ---
// Grid 512 x 256thr (24576/48). Wave owns all 48 rows (av[3][7] = 84 VGPR)
// x private o-quarter (38 tiles of 16 N-rows). 21 MFMA/tile (-25% vs padded
// 64-row blocks). Batches of 6 straddle fragment/q boundaries; min-over-6 =
// min(F full-frag-min, H adjacent half-min) combined via shfl_xor(16) and
// shfl_xor(48) with static q-dependent selects:
//   b0=min(F0@q0,H0lo@q1) b1=min(H0hi@q1,F0@q2) b2=min(F0@q3,H1lo@q0)
//   b3=min(H1hi@q0,F1@q1) b4=min(F1@q2,H1lo@q3) b5=min(H1hi@q3,F2@q0)
//   b6=min(F2@q1,H2lo@q2) b7=min(H2hi@q2,F2@q3)
// Pipelined epilogue (r14 schedule) kept. Per-row dots + min operands are
// numerically identical to round 16 -> absmax unchanged.
// LDS: A 21504 | gbfw2 @21504 (9728) | scsh @31232 (1792) = 33024.
__launch_bounds__(256, 2)
__global__ void k3_mfma(const _Float16* __restrict__ m_raw,
                        const float* __restrict__ gshad,
                        const float* __restrict__ gamma,
                        const float* __restrict__ beta,
                        const _Float16* __restrict__ W_h,
                        const float* __restrict__ gb,
                        const float* __restrict__ fW,
                        float* __restrict__ out)
{
    __shared__ __align__(16) char smem[33024];
    float2* gbfw2 = (float2*)(smem + 21504);
    float*  scsh  = (float*)(smem + 31232);

    const int t = threadIdx.x, lane = t & 63, wave = t >> 6;
    const int q = lane >> 4, cx = lane & 15;
    const int rdsw = (q ^ ((cx >> 1) & 3)) * 8;

    // ---- inlined BN finalize ----
    if (t < 224) {
        float sc = 0.f, sh = 0.f;
        if (t < NF) {
            float s = 0.f, qq = 0.f;
            #pragma unroll
            for (int c = 0; c < 16; ++c) { s += gshad[c*400 + t]; qq += gshad[c*400 + 200 + t]; }
            float inv = 1.0f / (float)NROWS;
            float mu  = s * inv;
            float var = qq * inv - mu*mu;
            float rs  = rsqrtf(var + BN_EPS);
            sc = rs * gamma[t];
            sh = beta[t] - mu*sc;
        }
        scsh[t] = sc; scsh[224 + t] = sh;
    }
    for (int i = t; i < 1216; i += 256) {
        float g = (i < FC) ? gb[i] : 0.f;
        float f = (i < FC) ? fW[i] : 0.f;
        gbfw2[i] = make_float2(g, f);
    }
    __syncthreads();

    // ---- build swizzled A panel (48 REAL rows x 224 f16) ----
    {
        _Float16* sa = (_Float16*)smem;
        for (int c = t; c < 1344; c += 256) {          // 48 rows x 28 chunks
            int row = c / 28, s = c - row*28;
            int key = (row >> 1) & 3;
            int col = (s >> 2)*32 + ((s & 3) ^ key)*8;
            half8 o;
            #pragma unroll
            for (int j = 0; j < 8; ++j) o[j] = (_Float16)0.f;
            if (s < 25) {
                int R = blockIdx.x*48 + row;
                half8 in = *(const half8*)&m_raw[(size_t)R*NF + s*8];
                #pragma unroll
                for (int j = 0; j < 8; ++j) {
                    int k = s*8 + j;
                    o[j] = (_Float16)fmaxf((float)in[j]*scsh[k] + scsh[224+k], 0.f);
                }
            }
            *(half8*)&sa[row*KP + col] = o;
        }
    }
    __syncthreads();

    // ---- hoist A fragments (3 mf x 7 ks): rows mf*16+cx ----
    f32x4 av[3][7];
    {
        const _Float16* sa = (const _Float16*)smem;
        #pragma unroll
        for (int mf = 0; mf < 3; ++mf) {
            int row = mf*16 + cx;
            #pragma unroll
            for (int ks = 0; ks < 7; ++ks)
                av[mf][ks] = *(const f32x4*)&sa[row*KP + ks*32 + rdsw];
        }
    }

    // ---- per-wave o-quarter, coalesced B direct to regs ----
    const int nbase = wave * (NPAD/4);                 // 608 N-rows per wave
    const char* wsrc = (const char*)W_h + (size_t)nbase * 448;  // tile-major
    const int boff = cx*64 + q*16;                     // within-1KB lane offset

    #define LOADT(BV_, NT_) do {                                             \
        const char* _b = wsrc + (size_t)(NT_)*7168 + boff;                   \
        _Pragma("unroll")                                                    \
        for (int _k = 0; _k < 7; ++_k)                                       \
            BV_[_k] = *(const f32x4*)(_b + _k*1024);                         \
    } while (0)

    #define MFMAT(BV_, ACC_) do {                                            \
        _Pragma("unroll")                                                    \
        for (int _m = 0; _m < 3; ++_m) ACC_[_m] = (f32x4){0.f,0.f,0.f,0.f};  \
        _Pragma("unroll")                                                    \
        for (int _k = 0; _k < 7; ++_k) {                                     \
            _Pragma("unroll")                                                \
            for (int _m = 0; _m < 3; ++_m)                                   \
                ACC_[_m] = __builtin_amdgcn_mfma_f32_16x16x32_f16(           \
                    __builtin_bit_cast(half8, av[_m][_k]),                   \
                    __builtin_bit_cast(half8, BV_[_k]), ACC_[_m], 0, 0, 0);  \
        }                                                                    \
    } while (0)

    float preg16 = 0.f, preg48 = 0.f;

    #define EPI(ACC_, NT_) do {                                              \
        float _h0l = fminf(ACC_[0][0], ACC_[0][1]);                          \
        float _h0h = fminf(ACC_[0][2], ACC_[0][3]);                          \
        float _h1l = fminf(ACC_[1][0], ACC_[1][1]);                          \
        float _h1h = fminf(ACC_[1][2], ACC_[1][3]);                          \
        float _h2l = fminf(ACC_[2][0], ACC_[2][1]);                          \
        float _h2h = fminf(ACC_[2][2], ACC_[2][3]);                          \
        float _f0 = fminf(_h0l, _h0h);                                       \
        float _f1 = fminf(_h1l, _h1h);                                       \
        float _f2 = fminf(_h2l, _h2h);                                       \
        float _u16 = (q==0) ? _h1h : (q==1) ? _h0l : (q==2) ? _h2h : _h1l;   \
        float _u48 = (q==0) ? _h1l : (q==1) ? _h0h : (q==2) ? _h2l : _h1h;   \
        float _F16 = (q==0) ? _f0 : (q==3) ? _f2 : _f1;                      \
        float _F48 = (q<=1) ? _f2 : _f0;                                     \
        float _v16 = fminf(_F16, __shfl_xor(_u16, 16));                      \
        float _v48 = fminf(_F48, __shfl_xor(_u48, 48));                      \
        float _vp16 = _v16 + __shfl_xor(_v16, 1);                            \
        float _vp48 = _v48 + __shfl_xor(_v48, 1);                            \
        float2 _gf = gbfw2[(nbase + (NT_)*16 + cx) >> 1];                    \
        if ((cx & 1) == 0) {                                                 \
            preg16 += fmaxf(_vp16 + _gf.x, 0.f) * _gf.y;                     \
            preg48 += fmaxf(_vp48 + _gf.x, 0.f) * _gf.y;                     \
        }                                                                    \
    } while (0)

    f32x4 bv0[7], bv1[7];
    f32x4 acc0[3], acc1[3];

    LOADT(bv0, 0);
    LOADT(bv1, 1);
    MFMAT(bv0, acc0);                       // tile 0
    // steps nt = 1..34 (17 pairs): LOAD(nt+1) | MFMA(nt) | EPI(nt-1)
    for (int k = 0; k < 17; ++k) {
        int nt = 2*k + 1;
        LOADT(bv0, nt + 1); MFMAT(bv1, acc1); EPI(acc0, nt - 1);
        LOADT(bv1, nt + 2); MFMAT(bv0, acc0); EPI(acc1, nt);
    }
    // tail: nt = 35, 36, 37
    LOADT(bv0, 36); MFMAT(bv1, acc1); EPI(acc0, 34);
    LOADT(bv1, 37); MFMAT(bv0, acc0); EPI(acc1, 35);
    MFMAT(bv1, acc1); EPI(acc0, 36);
    EPI(acc1, 37);

    // final: sum over cx (odd lanes hold 0), then atomics for this q's batches
    preg16 += __shfl_xor(preg16, 1); preg16 += __shfl_xor(preg16, 2);
    preg16 += __shfl_xor(preg16, 4); preg16 += __shfl_xor(preg16, 8);
    preg48 += __shfl_xor(preg48, 1); preg48 += __shfl_xor(preg48, 2);
    preg48 += __shfl_xor(preg48, 4); preg48 += __shfl_xor(preg48, 8);
    if (cx == 0) {
        int b16 = (q==0) ? 0 : (q==1) ? 3 : (q==2) ? 4 : 7;
        int b48 = (q==0) ? 5 : (q==1) ? 6 : (q==2) ? 1 : 2;
        atomicAdd(&out[blockIdx.x*8 + b16], preg16);
        atomicAdd(&out[blockIdx.x*8 + b48], preg48);
    }
}

extern "C" void kernel_launch(void* const* d_in, const int* in_sizes, int n_in,
                              void* d_out, int out_size, void* d_ws, size_t ws_size,
                              hipStream_t stream)
{
    const int*   x   = (const int*)  d_in[0];
    const float* er  = (const float*)d_in[1];
    const float* ev  = (const float*)d_in[2];
    const float* cw  = (const float*)d_in[3];
    const float* cb  = (const float*)d_in[4];
    const float* gam = (const float*)d_in[5];
    const float* bet = (const float*)d_in[6];
    const float* gW  = (const float*)d_in[7];
    const float* gb  = (const float*)d_in[8];
    const float* fW  = (const float*)d_in[9];
    const float* fb  = (const float*)d_in[10];

    float* ws = (float*)d_ws;
    _Float16* m_raw = (_Float16*)(ws + MRAW_OFF);
    _Float16* W_h   = (_Float16*)(ws + WH_OFF);
    _Float16* wT    = (_Float16*)(ws + WT_OFF);
    float* gshad    = ws + STAT_OFF;
    float* out      = (float*)d_out;

    k0_prep<<<(K0_TOT + 255)/256, 256, 0, stream>>>(cw, gW, fb, wT, W_h, out, gshad);
    k1_mfma<<<NROWS/32, 256, 0, stream>>>(x, er, ev, wT, cb, m_raw, gshad);
    k3_mfma<<<NROWS/48, 256, 0, stream>>>(m_raw, gshad, gam, bet, W_h, gb, fW, out);
}

// Round 18
// 66.375 us; speedup vs baseline: 1.3102x; 1.0813x over previous
//
#include <hip/hip_runtime.h>
#include <hip/hip_bf16.h>
#include <hip/hip_fp16.h>

#define B_    4096
#define ARITY 6
#define EMB   100
#define NF    200
#define FC    1200
#define NROWS (B_*ARITY)      // 24576
#define NPAD  2432            // N rows of W_h (A/C pairs interleaved)
#define BN_EPS 1e-5f
#define KP    224
#define SENT  32768.0f
#define NTW   (NPAD/4/16)     // 38 tiles of 16 N-rows per wave (o-quarter)

typedef _Float16 half8 __attribute__((ext_vector_type(8)));
typedef float f32x4 __attribute__((ext_vector_type(4)));

// ws float offsets
#define MRAW_OFF 0              // m_raw f16 [24576][200] -> 2,457,600 f
#define WH_OFF   2457600        // W_h f16, tile-major coalesced (k3) -> 272,384 f
#define WT_OFF   2729984        // wT  f16 [ks][hi|lo][224][32] swizzled (k1) -> 50,176 f
#define STAT_OFF 2780160        // gshad[16][400]

__device__ __forceinline__ void gload16(const void* g, void* l) {
    __builtin_amdgcn_global_load_lds(
        (const __attribute__((address_space(1))) void*)g,
        (__attribute__((address_space(3))) void*)l, 16, 0, 0);
}

__device__ __forceinline__ float4 ld4(const float* rr, const float* vr, int e) {
    if (e < EMB)        return *(const float4*)&rr[e];
    else if (e < 2*EMB) return *(const float4*)&vr[e - EMB];
    float4 z = {0.f,0.f,0.f,0.f}; return z;
}

// ---------------- k0: weight prep + out init + gshad zero ------------------
// (byte-identical to round 17)
#define K0_W1 (224*28)
#define K0_W2 (K0_W1 + NPAD*28)
#define K0_W3 (K0_W2 + B_)
#define K0_TOT (K0_W3 + 6400)
__launch_bounds__(256)
__global__ void k0_prep(const float* __restrict__ cw, const float* __restrict__ gW,
                        const float* __restrict__ fb,
                        _Float16* __restrict__ wT,
                        _Float16* __restrict__ W_h, float* __restrict__ out,
                        float* __restrict__ gshad)
{
    int id = blockIdx.x * 256 + threadIdx.x;
    if (id < K0_W1) {
        int f = id / 28, s = id - f*28;
        int ks = s >> 2, ls = s & 3, key = (f >> 1) & 3;
        int off = ks*14336 + f*32 + ((ls ^ key)*8);
        half8 h, l;
        #pragma unroll
        for (int j = 0; j < 8; ++j) {
            int k = s*8 + j;
            float v = (f < NF && k < NF) ? cw[f*NF + k] : 0.f;
            _Float16 hi = (_Float16)v;
            h[j] = hi; l[j] = (_Float16)(v - (float)hi);
        }
        *(half8*)&wT[off] = h;
        *(half8*)&wT[off + 7168] = l;
    } else if (id < K0_W2) {
        int id2 = id - K0_W1;
        int n = id2 / 28, s = id2 - n*28;
        int o = n >> 1, hf = n & 1;
        int off = (n >> 4)*3584 + (s >> 2)*512 + (n & 15)*32 + (s & 3)*8;
        half8 h;
        #pragma unroll
        for (int j = 0; j < 8; ++j) {
            int k = s*8 + j;
            float v = 0.f;
            if (k < NF && n < 2*FC) v = gW[(size_t)o*400 + hf*200 + k];
            if (k == NF) v = SENT;
            h[j] = (_Float16)v;
        }
        *(half8*)&W_h[off] = h;
    } else if (id < K0_W3) {
        out[id - K0_W2] = fb[0];
    } else if (id < K0_TOT) {
        gshad[id - K0_W3] = 0.f;
    }
}

// ---------------- k1: gather + split-f16 MFMA conv + stats -----------------
// SINGLE-BUFFER staging: A panel built in the W buffer, hoisted (pinned),
// then per ks: STAGE -> __syncthreads -> compute -> __syncthreads.
// LDS 30528 B -> 5 blocks/CU (vs ring-2's 59KB -> 2). The per-step vmcnt
// drain is hidden by 2.5x resident waves (implicit wave-level overlap).
// Arithmetic identical to round 17 -> m_raw bit-identical.
__launch_bounds__(256)
__global__ void k1_mfma(const int* __restrict__ x,
                        const float* __restrict__ er,
                        const float* __restrict__ ev,
                        const _Float16* __restrict__ wT,
                        const float* __restrict__ cb,
                        _Float16* __restrict__ m_raw,
                        float* __restrict__ gshad)
{
    __shared__ __align__(16) char smem[30528];
    float* s_sum = (float*)(smem + 28672);
    float* s_sq  = (float*)(smem + 29472);
    int*   s_ri  = (int*)(smem + 30272);
    int*   s_vi  = (int*)(smem + 30400);

    const int t = threadIdx.x, lane = t & 63, wave = t >> 6;
    const int wm = wave >> 1, wn = wave & 1;
    const int R0 = blockIdx.x * 32;
    const int q = lane >> 4, cx = lane & 15;
    const int rdsw = (q ^ ((cx >> 1) & 3)) * 8;

    if (t < 32) {
        int R = R0 + t, b = R / ARITY, a = R - b * ARITY;
        bool is64 = ((x[1] | x[3] | x[5] | x[7]) == 0);
        int base = b * (2*ARITY) + 2*a;
        s_ri[t] = is64 ? x[2*base]     : x[base];
        s_vi[t] = is64 ? x[2*base + 2] : x[base + 1];
    }
    if (t < NF) { s_sum[t] = 0.f; s_sq[t] = 0.f; }
    __syncthreads();

    // ---- build A panel (32 rows x 224, hi+lo) in the W buffer, swizzled ----
    {
        _Float16* s_ahi = (_Float16*)smem;          // 32x224
        _Float16* s_alo = s_ahi + 7168;
        for (int c = t; c < 896; c += 256) {
            int row = c / 28, s = c - row*28;
            int key = (row >> 1) & 3;
            int col = (s >> 2)*32 + ((s & 3) ^ key)*8;
            const float* rr = er + (size_t)s_ri[row] * EMB;
            const float* vr = ev + (size_t)s_vi[row] * EMB;
            int e0 = s*8;
            float4 v0 = ld4(rr, vr, e0);
            float4 v1 = ld4(rr, vr, e0 + 4);
            half8 hi, lo;
            hi[0]=(_Float16)v0.x; lo[0]=(_Float16)(v0.x-(float)hi[0]);
            hi[1]=(_Float16)v0.y; lo[1]=(_Float16)(v0.y-(float)hi[1]);
            hi[2]=(_Float16)v0.z; lo[2]=(_Float16)(v0.z-(float)hi[2]);
            hi[3]=(_Float16)v0.w; lo[3]=(_Float16)(v0.w-(float)hi[3]);
            hi[4]=(_Float16)v1.x; lo[4]=(_Float16)(v1.x-(float)hi[4]);
            hi[5]=(_Float16)v1.y; lo[5]=(_Float16)(v1.y-(float)hi[5]);
            hi[6]=(_Float16)v1.z; lo[6]=(_Float16)(v1.z-(float)hi[6]);
            hi[7]=(_Float16)v1.w; lo[7]=(_Float16)(v1.w-(float)hi[7]);
            *(half8*)&s_ahi[row*KP + col] = hi;
            *(half8*)&s_alo[row*KP + col] = lo;
        }
    }
    __syncthreads();

    // ---- hoist A fragments (pin: buffer gets overwritten by W staging) ----
    f32x4 ah[7], al[7];
    {
        const _Float16* s_ahi = (const _Float16*)smem;
        const _Float16* s_alo = s_ahi + 7168;
        int arow = wm*16 + cx;
        #pragma unroll
        for (int ks = 0; ks < 7; ++ks) {
            ah[ks] = *(const f32x4*)&s_ahi[arow*KP + ks*32 + rdsw];
            al[ks] = *(const f32x4*)&s_alo[arow*KP + ks*32 + rdsw];
            asm volatile("" : "+v"(ah[ks]), "+v"(al[ks]));
        }
    }
    __syncthreads();   // all A reads complete before W staging overwrites

    #define STAGE_W(KS_) do {                                                \
        const char* _src = (const char*)wT + (size_t)(KS_) * 28672;          \
        _Pragma("unroll")                                                    \
        for (int _i = 0; _i < 7; ++_i) {                                     \
            int _j = wave + 4*_i;                                            \
            gload16(_src + (size_t)(_j*64 + lane)*16, smem + _j*1024);       \
        }                                                                    \
    } while (0)

    f32x4 acc[7];
    #pragma unroll
    for (int nf = 0; nf < 7; ++nf) acc[nf] = (f32x4){0.f,0.f,0.f,0.f};

    for (int ks = 0; ks < 7; ++ks) {
        STAGE_W(ks);
        __syncthreads();                       // drains vmcnt -> W visible

        const _Float16* wb = (const _Float16*)smem;
        #pragma unroll
        for (int nf = 0; nf < 7; ++nf) {
            int rb = (wn*112 + nf*16 + cx)*32 + rdsw;
            half8 bh = *(const half8*)&wb[rb];
            half8 bl = *(const half8*)&wb[7168 + rb];
            acc[nf] = __builtin_amdgcn_mfma_f32_16x16x32_f16(
                __builtin_bit_cast(half8, ah[ks]), bh, acc[nf], 0,0,0);
            acc[nf] = __builtin_amdgcn_mfma_f32_16x16x32_f16(
                __builtin_bit_cast(half8, ah[ks]), bl, acc[nf], 0,0,0);
            acc[nf] = __builtin_amdgcn_mfma_f32_16x16x32_f16(
                __builtin_bit_cast(half8, al[ks]), bh, acc[nf], 0,0,0);
        }
        __syncthreads();                       // drains lgkm -> reads done
    }

    // epilogue: +bias, write m_raw (f16), block stats
    #pragma unroll
    for (int nf = 0; nf < 7; ++nf) {
        int f = wn*112 + nf*16 + cx;
        bool valid = (f < NF);
        float bias = valid ? cb[f] : 0.f;
        float ps = 0.f, pq = 0.f;
        #pragma unroll
        for (int reg = 0; reg < 4; ++reg) {
            float vv = acc[nf][reg] + bias;
            if (valid) {
                int R = R0 + wm*16 + q*4 + reg;
                m_raw[(size_t)R*NF + f] = (_Float16)vv;
                ps += vv; pq += vv*vv;
            }
        }
        ps += __shfl_xor(ps, 16); ps += __shfl_xor(ps, 32);
        pq += __shfl_xor(pq, 16); pq += __shfl_xor(pq, 32);
        if (valid && q == 0) { atomicAdd(&s_sum[f], ps); atomicAdd(&s_sq[f], pq); }
    }
    __syncthreads();
    if (t < NF) {
        float* g = gshad + (blockIdx.x & 15) * 400;
        atomicAdd(&g[t], s_sum[t]);
        atomicAdd(&g[t + 200], s_sq[t]);
    }
}

// ---------------- k3: 48-row blocks, distance-2 B prefetch -----------------
// Round-17 structure with a THIRD bv bank: line invariant
//   LOAD(L into bv[L%3]) | MFMA(L-2 from bv[(L-2)%3] -> acc[(L-2)%2]) | EPI(L-3)
// gives 2 tiles (~500 cyc) of load-to-use cover vs distance-1's ~250.
// EPI order unchanged -> preg bit-identical. Loads clamp at tile NTW-1.
// LDS: A 21504 | gbfw2 @21504 (9728) | scsh @31232 (1792) = 33024.
__launch_bounds__(256, 2)
__global__ void k3_mfma(const _Float16* __restrict__ m_raw,
                        const float* __restrict__ gshad,
                        const float* __restrict__ gamma,
                        const float* __restrict__ beta,
                        const _Float16* __restrict__ W_h,
                        const float* __restrict__ gb,
                        const float* __restrict__ fW,
                        float* __restrict__ out)
{
    __shared__ __align__(16) char smem[33024];
    float2* gbfw2 = (float2*)(smem + 21504);
    float*  scsh  = (float*)(smem + 31232);

    const int t = threadIdx.x, lane = t & 63, wave = t >> 6;
    const int q = lane >> 4, cx = lane & 15;
    const int rdsw = (q ^ ((cx >> 1) & 3)) * 8;

    // ---- inlined BN finalize ----
    if (t < 224) {
        float sc = 0.f, sh = 0.f;
        if (t < NF) {
            float s = 0.f, qq = 0.f;
            #pragma unroll
            for (int c = 0; c < 16; ++c) { s += gshad[c*400 + t]; qq += gshad[c*400 + 200 + t]; }
            float inv = 1.0f / (float)NROWS;
            float mu  = s * inv;
            float var = qq * inv - mu*mu;
            float rs  = rsqrtf(var + BN_EPS);
            sc = rs * gamma[t];
            sh = beta[t] - mu*sc;
        }
        scsh[t] = sc; scsh[224 + t] = sh;
    }
    for (int i = t; i < 1216; i += 256) {
        float g = (i < FC) ? gb[i] : 0.f;
        float f = (i < FC) ? fW[i] : 0.f;
        gbfw2[i] = make_float2(g, f);
    }
    __syncthreads();

    // ---- build swizzled A panel (48 REAL rows x 224 f16) ----
    {
        _Float16* sa = (_Float16*)smem;
        for (int c = t; c < 1344; c += 256) {
            int row = c / 28, s = c - row*28;
            int key = (row >> 1) & 3;
            int col = (s >> 2)*32 + ((s & 3) ^ key)*8;
            half8 o;
            #pragma unroll
            for (int j = 0; j < 8; ++j) o[j] = (_Float16)0.f;
            if (s < 25) {
                int R = blockIdx.x*48 + row;
                half8 in = *(const half8*)&m_raw[(size_t)R*NF + s*8];
                #pragma unroll
                for (int j = 0; j < 8; ++j) {
                    int k = s*8 + j;
                    o[j] = (_Float16)fmaxf((float)in[j]*scsh[k] + scsh[224+k], 0.f);
                }
            }
            *(half8*)&sa[row*KP + col] = o;
        }
    }
    __syncthreads();

    // ---- hoist A fragments (3 mf x 7 ks) ----
    f32x4 av[3][7];
    {
        const _Float16* sa = (const _Float16*)smem;
        #pragma unroll
        for (int mf = 0; mf < 3; ++mf) {
            int row = mf*16 + cx;
            #pragma unroll
            for (int ks = 0; ks < 7; ++ks)
                av[mf][ks] = *(const f32x4*)&sa[row*KP + ks*32 + rdsw];
        }
    }

    const int nbase = wave * (NPAD/4);
    const char* wsrc = (const char*)W_h + (size_t)nbase * 448;
    const int boff = cx*64 + q*16;

    #define LOADT(BV_, NT_) do {                                             \
        int _nt = (NT_) > (NTW-1) ? (NTW-1) : (NT_);                         \
        const char* _b = wsrc + (size_t)_nt*7168 + boff;                     \
        _Pragma("unroll")                                                    \
        for (int _k = 0; _k < 7; ++_k)                                       \
            BV_[_k] = *(const f32x4*)(_b + _k*1024);                         \
    } while (0)

    #define MFMAT(BV_, ACC_) do {                                            \
        _Pragma("unroll")                                                    \
        for (int _m = 0; _m < 3; ++_m) ACC_[_m] = (f32x4){0.f,0.f,0.f,0.f};  \
        _Pragma("unroll")                                                    \
        for (int _k = 0; _k < 7; ++_k) {                                     \
            _Pragma("unroll")                                                \
            for (int _m = 0; _m < 3; ++_m)                                   \
                ACC_[_m] = __builtin_amdgcn_mfma_f32_16x16x32_f16(           \
                    __builtin_bit_cast(half8, av[_m][_k]),                   \
                    __builtin_bit_cast(half8, BV_[_k]), ACC_[_m], 0, 0, 0);  \
        }                                                                    \
    } while (0)

    float preg16 = 0.f, preg48 = 0.f;

    #define EPI(ACC_, NT_) do {                                              \
        float _h0l = fminf(ACC_[0][0], ACC_[0][1]);                          \
        float _h0h = fminf(ACC_[0][2], ACC_[0][3]);                          \
        float _h1l = fminf(ACC_[1][0], ACC_[1][1]);                          \
        float _h1h = fminf(ACC_[1][2], ACC_[1][3]);                          \
        float _h2l = fminf(ACC_[2][0], ACC_[2][1]);                          \
        float _h2h = fminf(ACC_[2][2], ACC_[2][3]);                          \
        float _f0 = fminf(_h0l, _h0h);                                       \
        float _f1 = fminf(_h1l, _h1h);                                       \
        float _f2 = fminf(_h2l, _h2h);                                       \
        float _u16 = (q==0) ? _h1h : (q==1) ? _h0l : (q==2) ? _h2h : _h1l;   \
        float _u48 = (q==0) ? _h1l : (q==1) ? _h0h : (q==2) ? _h2l : _h1h;   \
        float _F16 = (q==0) ? _f0 : (q==3) ? _f2 : _f1;                      \
        float _F48 = (q<=1) ? _f2 : _f0;                                     \
        float _v16 = fminf(_F16, __shfl_xor(_u16, 16));                      \
        float _v48 = fminf(_F48, __shfl_xor(_u48, 48));                      \
        float _vp16 = _v16 + __shfl_xor(_v16, 1);                            \
        float _vp48 = _v48 + __shfl_xor(_v48, 1);                            \
        float2 _gf = gbfw2[(nbase + (NT_)*16 + cx) >> 1];                    \
        if ((cx & 1) == 0) {                                                 \
            preg16 += fmaxf(_vp16 + _gf.x, 0.f) * _gf.y;                     \
            preg48 += fmaxf(_vp48 + _gf.x, 0.f) * _gf.y;                     \
        }                                                                    \
    } while (0)

    f32x4 bv0[7], bv1[7], bv2[7];
    f32x4 acc0[3], acc1[3];

    LOADT(bv0, 0); LOADT(bv1, 1); LOADT(bv2, 2);
    MFMAT(bv0, acc0);                              // tile 0
    // 36 lines (L = 3..38) in 6 iterations of the period-6 pattern:
    for (int k = 0; k < 6; ++k) {
        int nt = 6*k;
        LOADT(bv0, nt + 3); MFMAT(bv1, acc1); EPI(acc0, nt + 0);
        LOADT(bv1, nt + 4); MFMAT(bv2, acc0); EPI(acc1, nt + 1);
        LOADT(bv2, nt + 5); MFMAT(bv0, acc1); EPI(acc0, nt + 2);
        LOADT(bv0, nt + 6); MFMAT(bv1, acc0); EPI(acc1, nt + 3);
        LOADT(bv1, nt + 7); MFMAT(bv2, acc1); EPI(acc0, nt + 4);
        LOADT(bv2, nt + 8); MFMAT(bv0, acc0); EPI(acc1, nt + 5);
    }
    // tail: tile 37 (in bv1, loaded at k=5 line 5), then final EPIs
    MFMAT(bv1, acc1); EPI(acc0, 36);
    EPI(acc1, 37);

    preg16 += __shfl_xor(preg16, 1); preg16 += __shfl_xor(preg16, 2);
    preg16 += __shfl_xor(preg16, 4); preg16 += __shfl_xor(preg16, 8);
    preg48 += __shfl_xor(preg48, 1); preg48 += __shfl_xor(preg48, 2);
    preg48 += __shfl_xor(preg48, 4); preg48 += __shfl_xor(preg48, 8);
    if (cx == 0) {
        int b16 = (q==0) ? 0 : (q==1) ? 3 : (q==2) ? 4 : 7;
        int b48 = (q==0) ? 5 : (q==1) ? 6 : (q==2) ? 1 : 2;
        atomicAdd(&out[blockIdx.x*8 + b16], preg16);
        atomicAdd(&out[blockIdx.x*8 + b48], preg48);
    }
}

extern "C" void kernel_launch(void* const* d_in, const int* in_sizes, int n_in,
                              void* d_out, int out_size, void* d_ws, size_t ws_size,
                              hipStream_t stream)
{
    const int*   x   = (const int*)  d_in[0];
    const float* er  = (const float*)d_in[1];
    const float* ev  = (const float*)d_in[2];
    const float* cw  = (const float*)d_in[3];
    const float* cb  = (const float*)d_in[4];
    const float* gam = (const float*)d_in[5];
    const float* bet = (const float*)d_in[6];
    const float* gW  = (const float*)d_in[7];
    const float* gb  = (const float*)d_in[8];
    const float* fW  = (const float*)d_in[9];
    const float* fb  = (const float*)d_in[10];

    float* ws = (float*)d_ws;
    _Float16* m_raw = (_Float16*)(ws + MRAW_OFF);
    _Float16* W_h   = (_Float16*)(ws + WH_OFF);
    _Float16* wT    = (_Float16*)(ws + WT_OFF);
    float* gshad    = ws + STAT_OFF;
    float* out      = (float*)d_out;

    k0_prep<<<(K0_TOT + 255)/256, 256, 0, stream>>>(cw, gW, fb, wT, W_h, out, gshad);
    k1_mfma<<<NROWS/32, 256, 0, stream>>>(x, er, ev, wT, cb, m_raw, gshad);
    k3_mfma<<<NROWS/48, 256, 0, stream>>>(m_raw, gshad, gam, bet, W_h, gb, fW, out);
}

// Round 19
// 65.653 us; speedup vs baseline: 1.3246x; 1.0110x over previous
//
#include <hip/hip_runtime.h>
#include <hip/hip_bf16.h>
#include <hip/hip_fp16.h>

#define B_    4096
#define ARITY 6
#define EMB   100
#define NF    200
#define FC    1200
#define NROWS (B_*ARITY)      // 24576
#define NPAD  2432            // N rows of W_h (A/C pairs interleaved)
#define BN_EPS 1e-5f
#define KP    224
#define SENT  32768.0f
#define NTW   (NPAD/4/16)     // 38 tiles of 16 N-rows per wave (o-quarter)

typedef _Float16 half8 __attribute__((ext_vector_type(8)));
typedef float f32x4 __attribute__((ext_vector_type(4)));

// ws float offsets
#define MRAW_OFF 0              // m_raw f16 [24576][200] -> 2,457,600 f
#define WH_OFF   2457600        // W_h f16, tile-major coalesced (k3) -> 272,384 f
#define WT_OFF   2729984        // wT  f16 [ks][hi|lo][224][32] swizzled (k1) -> 50,176 f
#define STAT_OFF 2780160        // gshad[16][400]

__device__ __forceinline__ void gload16(const void* g, void* l) {
    __builtin_amdgcn_global_load_lds(
        (const __attribute__((address_space(1))) void*)g,
        (__attribute__((address_space(3))) void*)l, 16, 0, 0);
}

__device__ __forceinline__ float4 ld4(const float* rr, const float* vr, int e) {
    if (e < EMB)        return *(const float4*)&rr[e];
    else if (e < 2*EMB) return *(const float4*)&vr[e - EMB];
    float4 z = {0.f,0.f,0.f,0.f}; return z;
}

// ---------------- k0: weight prep + out init + gshad zero ------------------
// (byte-identical to round 18)
#define K0_W1 (224*28)
#define K0_W2 (K0_W1 + NPAD*28)
#define K0_W3 (K0_W2 + B_)
#define K0_TOT (K0_W3 + 6400)
__launch_bounds__(256)
__global__ void k0_prep(const float* __restrict__ cw, const float* __restrict__ gW,
                        const float* __restrict__ fb,
                        _Float16* __restrict__ wT,
                        _Float16* __restrict__ W_h, float* __restrict__ out,
                        float* __restrict__ gshad)
{
    int id = blockIdx.x * 256 + threadIdx.x;
    if (id < K0_W1) {
        int f = id / 28, s = id - f*28;
        int ks = s >> 2, ls = s & 3, key = (f >> 1) & 3;
        int off = ks*14336 + f*32 + ((ls ^ key)*8);
        half8 h, l;
        #pragma unroll
        for (int j = 0; j < 8; ++j) {
            int k = s*8 + j;
            float v = (f < NF && k < NF) ? cw[f*NF + k] : 0.f;
            _Float16 hi = (_Float16)v;
            h[j] = hi; l[j] = (_Float16)(v - (float)hi);
        }
        *(half8*)&wT[off] = h;
        *(half8*)&wT[off + 7168] = l;
    } else if (id < K0_W2) {
        int id2 = id - K0_W1;
        int n = id2 / 28, s = id2 - n*28;
        int o = n >> 1, hf = n & 1;
        int off = (n >> 4)*3584 + (s >> 2)*512 + (n & 15)*32 + (s & 3)*8;
        half8 h;
        #pragma unroll
        for (int j = 0; j < 8; ++j) {
            int k = s*8 + j;
            float v = 0.f;
            if (k < NF && n < 2*FC) v = gW[(size_t)o*400 + hf*200 + k];
            if (k == NF) v = SENT;
            h[j] = (_Float16)v;
        }
        *(half8*)&W_h[off] = h;
    } else if (id < K0_W3) {
        out[id - K0_W2] = fb[0];
    } else if (id < K0_TOT) {
        gshad[id - K0_W3] = 0.f;
    }
}

// ---------------- k1: gather + split-f16 MFMA conv + stats -----------------
// (byte-identical to round 18 -- single-buffer staging, 5 blocks/CU)
__launch_bounds__(256)
__global__ void k1_mfma(const int* __restrict__ x,
                        const float* __restrict__ er,
                        const float* __restrict__ ev,
                        const _Float16* __restrict__ wT,
                        const float* __restrict__ cb,
                        _Float16* __restrict__ m_raw,
                        float* __restrict__ gshad)
{
    __shared__ __align__(16) char smem[30528];
    float* s_sum = (float*)(smem + 28672);
    float* s_sq  = (float*)(smem + 29472);
    int*   s_ri  = (int*)(smem + 30272);
    int*   s_vi  = (int*)(smem + 30400);

    const int t = threadIdx.x, lane = t & 63, wave = t >> 6;
    const int wm = wave >> 1, wn = wave & 1;
    const int R0 = blockIdx.x * 32;
    const int q = lane >> 4, cx = lane & 15;
    const int rdsw = (q ^ ((cx >> 1) & 3)) * 8;

    if (t < 32) {
        int R = R0 + t, b = R / ARITY, a = R - b * ARITY;
        bool is64 = ((x[1] | x[3] | x[5] | x[7]) == 0);
        int base = b * (2*ARITY) + 2*a;
        s_ri[t] = is64 ? x[2*base]     : x[base];
        s_vi[t] = is64 ? x[2*base + 2] : x[base + 1];
    }
    if (t < NF) { s_sum[t] = 0.f; s_sq[t] = 0.f; }
    __syncthreads();

    {
        _Float16* s_ahi = (_Float16*)smem;          // 32x224
        _Float16* s_alo = s_ahi + 7168;
        for (int c = t; c < 896; c += 256) {
            int row = c / 28, s = c - row*28;
            int key = (row >> 1) & 3;
            int col = (s >> 2)*32 + ((s & 3) ^ key)*8;
            const float* rr = er + (size_t)s_ri[row] * EMB;
            const float* vr = ev + (size_t)s_vi[row] * EMB;
            int e0 = s*8;
            float4 v0 = ld4(rr, vr, e0);
            float4 v1 = ld4(rr, vr, e0 + 4);
            half8 hi, lo;
            hi[0]=(_Float16)v0.x; lo[0]=(_Float16)(v0.x-(float)hi[0]);
            hi[1]=(_Float16)v0.y; lo[1]=(_Float16)(v0.y-(float)hi[1]);
            hi[2]=(_Float16)v0.z; lo[2]=(_Float16)(v0.z-(float)hi[2]);
            hi[3]=(_Float16)v0.w; lo[3]=(_Float16)(v0.w-(float)hi[3]);
            hi[4]=(_Float16)v1.x; lo[4]=(_Float16)(v1.x-(float)hi[4]);
            hi[5]=(_Float16)v1.y; lo[5]=(_Float16)(v1.y-(float)hi[5]);
            hi[6]=(_Float16)v1.z; lo[6]=(_Float16)(v1.z-(float)hi[6]);
            hi[7]=(_Float16)v1.w; lo[7]=(_Float16)(v1.w-(float)hi[7]);
            *(half8*)&s_ahi[row*KP + col] = hi;
            *(half8*)&s_alo[row*KP + col] = lo;
        }
    }
    __syncthreads();

    f32x4 ah[7], al[7];
    {
        const _Float16* s_ahi = (const _Float16*)smem;
        const _Float16* s_alo = s_ahi + 7168;
        int arow = wm*16 + cx;
        #pragma unroll
        for (int ks = 0; ks < 7; ++ks) {
            ah[ks] = *(const f32x4*)&s_ahi[arow*KP + ks*32 + rdsw];
            al[ks] = *(const f32x4*)&s_alo[arow*KP + ks*32 + rdsw];
            asm volatile("" : "+v"(ah[ks]), "+v"(al[ks]));
        }
    }
    __syncthreads();

    #define STAGE_W(KS_) do {                                                \
        const char* _src = (const char*)wT + (size_t)(KS_) * 28672;          \
        _Pragma("unroll")                                                    \
        for (int _i = 0; _i < 7; ++_i) {                                     \
            int _j = wave + 4*_i;                                            \
            gload16(_src + (size_t)(_j*64 + lane)*16, smem + _j*1024);       \
        }                                                                    \
    } while (0)

    f32x4 acc[7];
    #pragma unroll
    for (int nf = 0; nf < 7; ++nf) acc[nf] = (f32x4){0.f,0.f,0.f,0.f};

    for (int ks = 0; ks < 7; ++ks) {
        STAGE_W(ks);
        __syncthreads();

        const _Float16* wb = (const _Float16*)smem;
        #pragma unroll
        for (int nf = 0; nf < 7; ++nf) {
            int rb = (wn*112 + nf*16 + cx)*32 + rdsw;
            half8 bh = *(const half8*)&wb[rb];
            half8 bl = *(const half8*)&wb[7168 + rb];
            acc[nf] = __builtin_amdgcn_mfma_f32_16x16x32_f16(
                __builtin_bit_cast(half8, ah[ks]), bh, acc[nf], 0,0,0);
            acc[nf] = __builtin_amdgcn_mfma_f32_16x16x32_f16(
                __builtin_bit_cast(half8, ah[ks]), bl, acc[nf], 0,0,0);
            acc[nf] = __builtin_amdgcn_mfma_f32_16x16x32_f16(
                __builtin_bit_cast(half8, al[ks]), bh, acc[nf], 0,0,0);
        }
        __syncthreads();
    }

    #pragma unroll
    for (int nf = 0; nf < 7; ++nf) {
        int f = wn*112 + nf*16 + cx;
        bool valid = (f < NF);
        float bias = valid ? cb[f] : 0.f;
        float ps = 0.f, pq = 0.f;
        #pragma unroll
        for (int reg = 0; reg < 4; ++reg) {
            float vv = acc[nf][reg] + bias;
            if (valid) {
                int R = R0 + wm*16 + q*4 + reg;
                m_raw[(size_t)R*NF + f] = (_Float16)vv;
                ps += vv; pq += vv*vv;
            }
        }
        ps += __shfl_xor(ps, 16); ps += __shfl_xor(ps, 32);
        pq += __shfl_xor(pq, 16); pq += __shfl_xor(pq, 32);
        if (valid && q == 0) { atomicAdd(&s_sum[f], ps); atomicAdd(&s_sq[f], pq); }
    }
    __syncthreads();
    if (t < NF) {
        float* g = gshad + (blockIdx.x & 15) * 400;
        atomicAdd(&g[t], s_sum[t]);
        atomicAdd(&g[t + 200], s_sq[t]);
    }
}

// ---------------- k3: 48-row blocks, 3 waves/SIMD + staggered tile order ---
// Register diet for __launch_bounds__(256,3) (168-reg cap -> 3 blocks/CU =
// 12 waves/CU): av[3][7]=84 + bv dbuf 2x28 + single acc 12 + misc ~ 166.
// (Distance-2 and dual-acc were proven null at 2 waves -- shed for free.)
// Per-block tile-order rotation rot=(blockIdx*7)%38 de-phases the 64 blocks
// per XCD streaming the same W_h (L2 line/bank contention hypothesis).
// Reorders the 38-term preg sum only (~1e-6 absmax shift).
// LDS: A 21504 | gbfw2 @21504 (9728) | scsh @31232 (1792) = 33024.
__launch_bounds__(256, 3)
__global__ void k3_mfma(const _Float16* __restrict__ m_raw,
                        const float* __restrict__ gshad,
                        const float* __restrict__ gamma,
                        const float* __restrict__ beta,
                        const _Float16* __restrict__ W_h,
                        const float* __restrict__ gb,
                        const float* __restrict__ fW,
                        float* __restrict__ out)
{
    __shared__ __align__(16) char smem[33024];
    float2* gbfw2 = (float2*)(smem + 21504);
    float*  scsh  = (float*)(smem + 31232);

    const int t = threadIdx.x, lane = t & 63, wave = t >> 6;
    const int q = lane >> 4, cx = lane & 15;
    const int rdsw = (q ^ ((cx >> 1) & 3)) * 8;
    const int rot = (blockIdx.x * 7) % NTW;

    // ---- inlined BN finalize ----
    if (t < 224) {
        float sc = 0.f, sh = 0.f;
        if (t < NF) {
            float s = 0.f, qq = 0.f;
            #pragma unroll
            for (int c = 0; c < 16; ++c) { s += gshad[c*400 + t]; qq += gshad[c*400 + 200 + t]; }
            float inv = 1.0f / (float)NROWS;
            float mu  = s * inv;
            float var = qq * inv - mu*mu;
            float rs  = rsqrtf(var + BN_EPS);
            sc = rs * gamma[t];
            sh = beta[t] - mu*sc;
        }
        scsh[t] = sc; scsh[224 + t] = sh;
    }
    for (int i = t; i < 1216; i += 256) {
        float g = (i < FC) ? gb[i] : 0.f;
        float f = (i < FC) ? fW[i] : 0.f;
        gbfw2[i] = make_float2(g, f);
    }
    __syncthreads();

    // ---- build swizzled A panel (48 REAL rows x 224 f16) ----
    {
        _Float16* sa = (_Float16*)smem;
        for (int c = t; c < 1344; c += 256) {
            int row = c / 28, s = c - row*28;
            int key = (row >> 1) & 3;
            int col = (s >> 2)*32 + ((s & 3) ^ key)*8;
            half8 o;
            #pragma unroll
            for (int j = 0; j < 8; ++j) o[j] = (_Float16)0.f;
            if (s < 25) {
                int R = blockIdx.x*48 + row;
                half8 in = *(const half8*)&m_raw[(size_t)R*NF + s*8];
                #pragma unroll
                for (int j = 0; j < 8; ++j) {
                    int k = s*8 + j;
                    o[j] = (_Float16)fmaxf((float)in[j]*scsh[k] + scsh[224+k], 0.f);
                }
            }
            *(half8*)&sa[row*KP + col] = o;
        }
    }
    __syncthreads();

    // ---- hoist A fragments (3 mf x 7 ks) ----
    f32x4 av[3][7];
    {
        const _Float16* sa = (const _Float16*)smem;
        #pragma unroll
        for (int mf = 0; mf < 3; ++mf) {
            int row = mf*16 + cx;
            #pragma unroll
            for (int ks = 0; ks < 7; ++ks)
                av[mf][ks] = *(const f32x4*)&sa[row*KP + ks*32 + rdsw];
        }
    }

    const int nbase = wave * (NPAD/4);
    const char* wsrc = (const char*)W_h + (size_t)nbase * 448;
    const int boff = cx*64 + q*16;

    // logical step -> physical tile (per-block rotation)
    #define PHYS(L_) (((L_) + rot) >= NTW ? ((L_) + rot) - NTW : ((L_) + rot))

    #define LOADT(BV_, L_) do {                                              \
        int _nt = PHYS((L_) < NTW ? (L_) : 0);                               \
        const char* _b = wsrc + (size_t)_nt*7168 + boff;                     \
        _Pragma("unroll")                                                    \
        for (int _k = 0; _k < 7; ++_k)                                       \
            BV_[_k] = *(const f32x4*)(_b + _k*1024);                         \
    } while (0)

    #define MFMAT(BV_, ACC_) do {                                            \
        _Pragma("unroll")                                                    \
        for (int _m = 0; _m < 3; ++_m) ACC_[_m] = (f32x4){0.f,0.f,0.f,0.f};  \
        _Pragma("unroll")                                                    \
        for (int _k = 0; _k < 7; ++_k) {                                     \
            _Pragma("unroll")                                                \
            for (int _m = 0; _m < 3; ++_m)                                   \
                ACC_[_m] = __builtin_amdgcn_mfma_f32_16x16x32_f16(           \
                    __builtin_bit_cast(half8, av[_m][_k]),                   \
                    __builtin_bit_cast(half8, BV_[_k]), ACC_[_m], 0, 0, 0);  \
        }                                                                    \
    } while (0)

    float preg16 = 0.f, preg48 = 0.f;

    #define EPI(ACC_, L_) do {                                               \
        float _h0l = fminf(ACC_[0][0], ACC_[0][1]);                          \
        float _h0h = fminf(ACC_[0][2], ACC_[0][3]);                          \
        float _h1l = fminf(ACC_[1][0], ACC_[1][1]);                          \
        float _h1h = fminf(ACC_[1][2], ACC_[1][3]);                          \
        float _h2l = fminf(ACC_[2][0], ACC_[2][1]);                          \
        float _h2h = fminf(ACC_[2][2], ACC_[2][3]);                          \
        float _f0 = fminf(_h0l, _h0h);                                       \
        float _f1 = fminf(_h1l, _h1h);                                       \
        float _f2 = fminf(_h2l, _h2h);                                       \
        float _u16 = (q==0) ? _h1h : (q==1) ? _h0l : (q==2) ? _h2h : _h1l;   \
        float _u48 = (q==0) ? _h1l : (q==1) ? _h0h : (q==2) ? _h2l : _h1h;   \
        float _F16 = (q==0) ? _f0 : (q==3) ? _f2 : _f1;                      \
        float _F48 = (q<=1) ? _f2 : _f0;                                     \
        float _v16 = fminf(_F16, __shfl_xor(_u16, 16));                      \
        float _v48 = fminf(_F48, __shfl_xor(_u48, 48));                      \
        float _vp16 = _v16 + __shfl_xor(_v16, 1);                            \
        float _vp48 = _v48 + __shfl_xor(_v48, 1);                            \
        float2 _gf = gbfw2[(nbase + PHYS(L_)*16 + cx) >> 1];                 \
        if ((cx & 1) == 0) {                                                 \
            preg16 += fmaxf(_vp16 + _gf.x, 0.f) * _gf.y;                     \
            preg48 += fmaxf(_vp48 + _gf.x, 0.f) * _gf.y;                     \
        }                                                                    \
    } while (0)

    f32x4 bv0[7], bv1[7];
    f32x4 acc[3];

    LOADT(bv0, 0);
    // steps L = 0..37: LOAD(L+1 into other bank) | MFMA(L) | EPI(L)
    for (int k = 0; k < 19; ++k) {
        int L = 2*k;
        LOADT(bv1, L + 1); MFMAT(bv0, acc); EPI(acc, L);
        LOADT(bv0, L + 2); MFMAT(bv1, acc); EPI(acc, L + 1);
    }

    preg16 += __shfl_xor(preg16, 1); preg16 += __shfl_xor(preg16, 2);
    preg16 += __shfl_xor(preg16, 4); preg16 += __shfl_xor(preg16, 8);
    preg48 += __shfl_xor(preg48, 1); preg48 += __shfl_xor(preg48, 2);
    preg48 += __shfl_xor(preg48, 4); preg48 += __shfl_xor(preg48, 8);
    if (cx == 0) {
        int b16 = (q==0) ? 0 : (q==1) ? 3 : (q==2) ? 4 : 7;
        int b48 = (q==0) ? 5 : (q==1) ? 6 : (q==2) ? 1 : 2;
        atomicAdd(&out[blockIdx.x*8 + b16], preg16);
        atomicAdd(&out[blockIdx.x*8 + b48], preg48);
    }
}

extern "C" void kernel_launch(void* const* d_in, const int* in_sizes, int n_in,
                              void* d_out, int out_size, void* d_ws, size_t ws_size,
                              hipStream_t stream)
{
    const int*   x   = (const int*)  d_in[0];
    const float* er  = (const float*)d_in[1];
    const float* ev  = (const float*)d_in[2];
    const float* cw  = (const float*)d_in[3];
    const float* cb  = (const float*)d_in[4];
    const float* gam = (const float*)d_in[5];
    const float* bet = (const float*)d_in[6];
    const float* gW  = (const float*)d_in[7];
    const float* gb  = (const float*)d_in[8];
    const float* fW  = (const float*)d_in[9];
    const float* fb  = (const float*)d_in[10];

    float* ws = (float*)d_ws;
    _Float16* m_raw = (_Float16*)(ws + MRAW_OFF);
    _Float16* W_h   = (_Float16*)(ws + WH_OFF);
    _Float16* wT    = (_Float16*)(ws + WT_OFF);
    float* gshad    = ws + STAT_OFF;
    float* out      = (float*)d_out;

    k0_prep<<<(K0_TOT + 255)/256, 256, 0, stream>>>(cw, gW, fb, wT, W_h, out, gshad);
    k1_mfma<<<NROWS/32, 256, 0, stream>>>(x, er, ev, wT, cb, m_raw, gshad);
    k3_mfma<<<NROWS/48, 256, 0, stream>>>(m_raw, gshad, gam, bet, W_h, gb, fW, out);
}